// Round 7
// baseline (4427.934 us; speedup 1.0000x reference)
//
#include <hip/hip_runtime.h>

// STA-LSTM forward: B=2048, S=128, D=64, H1=H2=128, OUT=1
// Round 7: NT=1024 (4 waves/SIMD) with allocator PINNED via amdgpu_waves_per_eu(4,4)
//          (round-4 spill was a one-sided launch_bounds minimum; 84KB LDS still
//          forces 1 block/CU). Per-thread work halved everywhere vs round 6.
//   repack_kernel: weights -> B-fragment-ordered split-bf16 in ws (~0.9 MB)
//   mf_ph12: phase 1 VALU attention + MFMA gates; phase 2 betas+h_att (VALU)
//   mf_ph3:  temporal LSTM, K=256 MFMA over [lh;ha]@[taU;taW]
//   Fallback to round-3 VALU kernels if ws too small.

#define BB 2048
#define SS 128
#define DD 64
#define HH 128
#define NG 512
#define M  8
#define NT 1024
#define NTF 512

#define A_OFF    ((size_t)BB)
#define BETA_OFF ((size_t)BB + (size_t)SS*BB*DD)
#define H_BYTES  ((size_t)BB*SS*HH*4)

// fragment buffer layout in ws (ushort offsets)
#define B1_ELEMS (192*512)
#define B3_ELEMS (256*512)
#define B1H_OFF 0
#define B1L_OFF (B1_ELEMS)
#define B3H_OFF (2*B1_ELEMS)
#define B3L_OFF (2*B1_ELEMS + B3_ELEMS)
#define FRAG_BYTES ((size_t)(2*B1_ELEMS + 2*B3_ELEMS)*2)   // 917504 B
#define NEED_BYTES (FRAG_BYTES + H_BYTES)

typedef float f32x4 __attribute__((ext_vector_type(4)));
typedef __bf16 bf16x8 __attribute__((ext_vector_type(8)));
union FB { uint4 u; bf16x8 v; };
__device__ __forceinline__ bf16x8 as_bf(uint4 u){ FB x; x.u = u; return x.v; }

__device__ __forceinline__ unsigned short bf16rne(float f){
  unsigned u = __float_as_uint(f);
  u = (u + 0x7FFFu + ((u >> 16) & 1u)) >> 16;
  return (unsigned short)u;
}
__device__ __forceinline__ float bfval(unsigned short h){
  return __uint_as_float(((unsigned)h) << 16);
}

__device__ __forceinline__ float sigf(float x){ return 1.0f/(1.0f + __expf(-x)); }
__device__ __forceinline__ float tanhx(float x){ return 1.0f - 2.0f/(1.0f + __expf(2.0f*x)); }

__device__ __forceinline__ float wmax64(float v){
#pragma unroll
  for (int m = 32; m; m >>= 1) v = fmaxf(v, __shfl_xor(v, m, 64));
  return v;
}
__device__ __forceinline__ float wsum64(float v){
#pragma unroll
  for (int m = 32; m; m >>= 1) v += __shfl_xor(v, m, 64);
  return v;
}

// ================= repack: weights -> fragment-ordered split-bf16 =================
__global__ __launch_bounds__(256) void repack_kernel(
    const float* __restrict__ saW, const float* __restrict__ saU,
    const float* __restrict__ taU, const float* __restrict__ taW,
    unsigned short* __restrict__ F)
{
  int id = blockIdx.x*256 + threadIdx.x;
  if (id < B1_ELEMS){
    int k = id >> 9, n = id & 511;
    float v = (k < DD) ? saW[(size_t)k*NG + n] : saU[(size_t)(k-DD)*NG + n];
    int kt = k >> 5, kw = k & 31, nt = n >> 4, nc = n & 15;
    int lane = ((kw >> 3) << 4) | nc, j = kw & 7;
    size_t off = ((size_t)(nt*6 + kt)*64 + lane)*8 + j;
    unsigned short hi = bf16rne(v);
    unsigned short lo = bf16rne(v - bfval(hi));
    F[B1H_OFF + off] = hi; F[B1L_OFF + off] = lo;
  }
  if (id < B3_ELEMS){
    int k = id >> 9, n = id & 511;
    float v = (k < HH) ? taU[(size_t)k*NG + n] : taW[(size_t)(k-HH)*NG + n];
    int kt = k >> 5, kw = k & 31, nt = n >> 4, nc = n & 15;
    int lane = ((kw >> 3) << 4) | nc, j = kw & 7;
    size_t off = ((size_t)(nt*8 + kt)*64 + lane)*8 + j;
    unsigned short hi = bf16rne(v);
    unsigned short lo = bf16rne(v - bfval(hi));
    F[B3H_OFF + off] = hi; F[B3L_OFF + off] = lo;
  }
}

// ================= mf_ph12: phase 1 (MFMA gates) + phase 2 =================
struct P1 {
  float x[M][DD];      // 2K
  float a[M][DD];      // 2K
  float h[M][HH];      // 4K
  float c[M][HH];      // 4K
  float xw[M][DD];     // 2K
  float g[M][NG];      // 16K
  float red[16][512];  // 32K
  float sbias[NG];     // 2K
  uint4 afh[6*64];     // 6K
  uint4 afl[6*64];     // 6K  -> 76K
};
struct P2 { float A[32][HH]; float tmp[32][SS]; float bp[32][SS]; };  // 48K
union __align__(16) SMA { P1 p1; P2 p2; float pad[21504]; };          // 84K -> 1 blk/CU

__global__ __launch_bounds__(NT) __attribute__((amdgpu_waves_per_eu(4, 4)))
void mf_ph12_kernel(
    const float* __restrict__ X,   const float* __restrict__ sab,
    const float* __restrict__ saWa, const float* __restrict__ saUa,
    const float* __restrict__ saba, const float* __restrict__ saVa,
    const float* __restrict__ taWa, const float* __restrict__ taba,
    const float* __restrict__ taVa,
    const unsigned short* __restrict__ Fr,
    float* __restrict__ out, float* __restrict__ Hws)
{
  __shared__ SMA sm;
  const int tid = threadIdx.x;
  const int b0  = blockIdx.x * M;
  const int w   = tid >> 6, l = tid & 63;   // 16 waves

  { int r = tid >> 7, j = tid & 127;
    sm.p1.h[r][j] = 0.f; sm.p1.c[r][j] = 0.f; }
  if (tid < NG) sm.p1.sbias[tid] = sab[tid];
  if (tid < 512){ int r = tid >> 6, d = tid & 63;
    sm.p1.x[r][d] = X[(size_t)(b0+r)*SS*DD + d]; }
  __syncthreads();

  for (int t = 0; t < SS; ++t){
    // ---- attn GEMM1 partials: 16-wave k-slices (x:4, h:8, c:8) ----
    {
      float pr[M];
#pragma unroll
      for (int r = 0; r < M; ++r) pr[r] = 0.f;
      { const int k = w*4;                         // x part
        const float* wp = saWa + (size_t)k*DD + l;
        float w0 = wp[0], w1 = wp[DD], w2 = wp[2*DD], w3 = wp[3*DD];
#pragma unroll
        for (int r = 0; r < M; ++r){
          float4 v = *(const float4*)&sm.p1.x[r][k];
          pr[r] += w0*v.x + w1*v.y + w2*v.z + w3*v.w;
        }
      }
#pragma unroll
      for (int q = 0; q < 2; ++q){                 // h part
        const int k = w*8 + q*4;
        const float* wp = saUa + (size_t)k*DD + l;
        float w0 = wp[0], w1 = wp[DD], w2 = wp[2*DD], w3 = wp[3*DD];
#pragma unroll
        for (int r = 0; r < M; ++r){
          float4 v = *(const float4*)&sm.p1.h[r][k];
          pr[r] += w0*v.x + w1*v.y + w2*v.z + w3*v.w;
        }
      }
#pragma unroll
      for (int q = 0; q < 2; ++q){                 // c part
        const int k = w*8 + q*4;
        const float* wp = saUa + (size_t)(HH + k)*DD + l;
        float w0 = wp[0], w1 = wp[DD], w2 = wp[2*DD], w3 = wp[3*DD];
#pragma unroll
        for (int r = 0; r < M; ++r){
          float4 v = *(const float4*)&sm.p1.c[r][k];
          pr[r] += w0*v.x + w1*v.y + w2*v.z + w3*v.w;
        }
      }
#pragma unroll
      for (int r = 0; r < M; ++r) sm.p1.red[w][r*64 + l] = pr[r];
    }
    __syncthreads();

    // ---- reduce1 + bias + tanh -> a (waves 0..7) ----
    if (tid < 512){
      const int r = tid >> 6, col = tid & 63;
      float s0 = saba[col], s1 = 0.f;
#pragma unroll
      for (int u = 0; u < 16; u += 2){
        s0 += sm.p1.red[u][r*64 + col];
        s1 += sm.p1.red[u+1][r*64 + col];
      }
      sm.p1.a[r][col] = tanhx(s0 + s1);
    }
    __syncthreads();

    // ---- attn GEMM2 partials: av = a @ saVa (16-wave k-slices of 4) ----
    {
      float pr[M];
#pragma unroll
      for (int r = 0; r < M; ++r) pr[r] = 0.f;
      const int k = w*4;
      const float* wp = saVa + (size_t)k*DD + l;
      float w0 = wp[0], w1 = wp[DD], w2 = wp[2*DD], w3 = wp[3*DD];
#pragma unroll
      for (int r = 0; r < M; ++r){
        float4 v = *(const float4*)&sm.p1.a[r][k];
        pr[r] += w0*v.x + w1*v.y + w2*v.z + w3*v.w;
      }
#pragma unroll
      for (int r = 0; r < M; ++r) sm.p1.red[w][r*64 + l] = pr[r];
    }
    __syncthreads();

    // ---- reduce2 + softmax + alphas out + xw (waves 0..7) ----
    if (tid < 512){
      const int r = tid >> 6, col = tid & 63;
      float s0 = 0.f, s1 = 0.f;
#pragma unroll
      for (int u = 0; u < 16; u += 2){
        s0 += sm.p1.red[u][r*64 + col];
        s1 += sm.p1.red[u+1][r*64 + col];
      }
      float s = s0 + s1;
      float mm = wmax64(s);
      float e  = __expf(s - mm);
      float al = e * (1.0f / wsum64(e));
      out[A_OFF + (size_t)t*BB*DD + (size_t)(b0+r)*DD + col] = al;
      sm.p1.xw[r][col] = al * sm.p1.x[r][col];
    }
    __syncthreads();

    // ---- A-frag build (384 thr) + x(t+1) stage (128 thr) ----
    if (tid < 384){
      const int kt = tid >> 6, lf = tid & 63;
      const int row = lf & 15, kg = lf >> 4;
      unsigned hh[4], lw[4];
      if (row < 8){
        const int kb = kt*32 + kg*8;
#pragma unroll
        for (int jp = 0; jp < 4; ++jp){
          int k0 = kb + jp*2;
          float v0 = (k0   < DD) ? sm.p1.xw[row][k0]   : sm.p1.h[row][k0-DD];
          float v1 = (k0+1 < DD) ? sm.p1.xw[row][k0+1] : sm.p1.h[row][k0+1-DD];
          unsigned short h0 = bf16rne(v0), h1 = bf16rne(v1);
          unsigned short l0 = bf16rne(v0 - bfval(h0)), l1 = bf16rne(v1 - bfval(h1));
          hh[jp] = (unsigned)h0 | ((unsigned)h1 << 16);
          lw[jp] = (unsigned)l0 | ((unsigned)l1 << 16);
        }
      } else {
#pragma unroll
        for (int jp = 0; jp < 4; ++jp){ hh[jp] = 0u; lw[jp] = 0u; }
      }
      sm.p1.afh[kt*64 + lf] = make_uint4(hh[0], hh[1], hh[2], hh[3]);
      sm.p1.afl[kt*64 + lf] = make_uint4(lw[0], lw[1], lw[2], lw[3]);
    } else if (tid < 512 && t + 1 < SS){
      int q = tid - 384;
      int r = q >> 4, d0 = (q & 15)*4;
      *(float4*)&sm.p1.x[r][d0] =
        *(const float4*)(X + (size_t)(b0+r)*SS*DD + (size_t)(t+1)*DD + d0);
    }
    __syncthreads();

    // ---- MFMA gates: [16x192]@[192x512], 16 waves x 2 n-tiles ----
    {
      f32x4 zero4 = {0.f, 0.f, 0.f, 0.f};
      f32x4 acc[2];
      acc[0] = zero4; acc[1] = zero4;
      const uint4* bh = ((const uint4*)(Fr + B1H_OFF)) + (size_t)(w*2)*6*64 + l;
      const uint4* bl = ((const uint4*)(Fr + B1L_OFF)) + (size_t)(w*2)*6*64 + l;
#pragma unroll
      for (int kt = 0; kt < 6; ++kt){
        bf16x8 vah = as_bf(sm.p1.afh[kt*64 + l]);
        bf16x8 val = as_bf(sm.p1.afl[kt*64 + l]);
#pragma unroll
        for (int n4 = 0; n4 < 2; ++n4){
          bf16x8 vbh = as_bf(bh[(n4*6 + kt)*64]);
          bf16x8 vbl = as_bf(bl[(n4*6 + kt)*64]);
          acc[n4] = __builtin_amdgcn_mfma_f32_16x16x32_bf16(vah, vbh, acc[n4], 0, 0, 0);
          acc[n4] = __builtin_amdgcn_mfma_f32_16x16x32_bf16(val, vbh, acc[n4], 0, 0, 0);
          acc[n4] = __builtin_amdgcn_mfma_f32_16x16x32_bf16(vah, vbl, acc[n4], 0, 0, 0);
        }
      }
      const int row0 = (l >> 4)*4;
      if (row0 < 8){
        const int colb = w*32 + (l & 15);
#pragma unroll
        for (int n4 = 0; n4 < 2; ++n4){
          int col = colb + n4*16;
          float b = sm.p1.sbias[col];
#pragma unroll
          for (int j = 0; j < 4; ++j) sm.p1.g[row0+j][col] = acc[n4][j] + b;
        }
      }
    }
    __syncthreads();

    // ---- LSTM pointwise + store H (1 elem/thread) ----
    {
      int r = tid >> 7, j = tid & 127;
      float iv = sigf (sm.p1.g[r][j]);
      float fv = sigf (sm.p1.g[r][j +   HH]);
      float gv = tanhx(sm.p1.g[r][j + 2*HH]);
      float ov = sigf (sm.p1.g[r][j + 3*HH]);
      float cn = fv * sm.p1.c[r][j] + iv * gv;
      float hn = ov * tanhx(cn);
      sm.p1.c[r][j] = cn; sm.p1.h[r][j] = hn;
      Hws[(size_t)(b0+r)*SS*HH + (size_t)t*HH + j] = hn;
    }
    __syncthreads();
  }

  // ================= Phase 2: betas + h_att (overwrites H in-place) =================
  for (int r = 0; r < M; ++r){
    float* Hrow = Hws + (size_t)(b0+r)*SS*HH;
    const int c  = tid & 127;
    const int th = tid >> 7;   // 0..7, owns rows th*4..th*4+3 of each 32-row chunk
    float hacc[16];
#pragma unroll
    for (int i = 0; i < 16; ++i) hacc[i] = 0.f;

#pragma unroll
    for (int ch = 0; ch < 4; ++ch){
      ((float4*)sm.p2.A)[tid] = ((const float4*)(Hrow + (size_t)ch*32*HH))[tid];
      __syncthreads();

      { // GEMM1: tmp = tanh(A @ taWa + taba)
        float acc[4];
        const float bv = taba[c];
#pragma unroll
        for (int i = 0; i < 4; ++i) acc[i] = bv;
        for (int k = 0; k < HH; k += 4){
          const float* wp = taWa + (size_t)k*SS + c;
          float w0 = wp[0], w1 = wp[SS], w2 = wp[2*SS], w3 = wp[3*SS];
#pragma unroll
          for (int i = 0; i < 4; ++i){
            float4 v = *(const float4*)&sm.p2.A[th*4+i][k];
            acc[i] += w0*v.x + w1*v.y + w2*v.z + w3*v.w;
          }
        }
#pragma unroll
        for (int i = 0; i < 4; ++i) sm.p2.tmp[th*4+i][c] = tanhx(acc[i]);
      }
      __syncthreads();

      { // GEMM2: bp = tmp @ taVa
        float acc[4];
#pragma unroll
        for (int i = 0; i < 4; ++i) acc[i] = 0.f;
        for (int k = 0; k < SS; k += 4){
          const float* wp = taVa + (size_t)k*SS + c;
          float w0 = wp[0], w1 = wp[SS], w2 = wp[2*SS], w3 = wp[3*SS];
#pragma unroll
          for (int i = 0; i < 4; ++i){
            float4 v = *(const float4*)&sm.p2.tmp[th*4+i][k];
            acc[i] += w0*v.x + w1*v.y + w2*v.z + w3*v.w;
          }
        }
#pragma unroll
        for (int i = 0; i < 4; ++i) sm.p2.bp[th*4+i][c] = acc[i];
      }
      __syncthreads();

      { // softmax rows -> beta ; write betas ; keep beta in LDS (16 waves x 2 rows)
        const int wv = tid >> 6, lane = tid & 63;
#pragma unroll
        for (int it = 0; it < 2; ++it){
          int tl = wv + 16*it;
          float v0 = sm.p2.bp[tl][lane], v1 = sm.p2.bp[tl][lane+64];
          float mm = wmax64(fmaxf(v0, v1));
          float e0 = __expf(v0 - mm), e1 = __expf(v1 - mm);
          float inv = 1.0f / wsum64(e0 + e1);
          e0 *= inv; e1 *= inv;
          size_t bo = BETA_OFF + (size_t)(ch*32+tl)*BB*SS + (size_t)(b0+r)*SS;
          out[bo + lane]      = e0;
          out[bo + lane + 64] = e1;
          sm.p2.bp[tl][lane]      = e0;
          sm.p2.bp[tl][lane + 64] = e1;
        }
      }
      __syncthreads();

      // GEMM3: h_att(chunk rows) += beta @ Hrow
      for (int k = 0; k < SS; k += 4){
        const float* hp = Hrow + (size_t)k*HH + c;
        float hv0 = hp[0], hv1 = hp[HH], hv2 = hp[2*HH], hv3 = hp[3*HH];
#pragma unroll
        for (int i = 0; i < 4; ++i){
          float4 bv = *(const float4*)&sm.p2.bp[th*4+i][k];
          hacc[ch*4+i] += bv.x*hv0 + bv.y*hv1 + bv.z*hv2 + bv.w*hv3;
        }
      }
    }
    __syncthreads();   // all Hrow reads complete before overwrite
#pragma unroll
    for (int ch = 0; ch < 4; ++ch)
#pragma unroll
      for (int i = 0; i < 4; ++i)
        Hrow[(size_t)(ch*32 + th*4 + i)*HH + c] = hacc[ch*4+i];
    __syncthreads();
  }
}

// ================= mf_ph3: temporal LSTM, K=256 MFMA ([lh;ha]@[taU;taW]) =============
struct P3 {
  float ha[2][M][HH];  // 8K (double-buffered)
  float lh[M][HH];     // 4K
  float lc[M][HH];     // 4K
  float g[M][NG];      // 16K
  float sb[NG];        // 2K (tab)
  float wy[NG];        // 2K (taWy)
  float fcv[HH];       // 0.5K
  float yp[M];
  uint4 afh[8*64];     // 8K
  uint4 afl[8*64];     // 8K
};
union __align__(16) SMC { P3 s; float pad[21504]; };   // 84K -> 1 blk/CU

__global__ __launch_bounds__(NT) __attribute__((amdgpu_waves_per_eu(4, 4)))
void mf_ph3_kernel(
    const float* __restrict__ X, const float* __restrict__ Ha,
    const unsigned short* __restrict__ Fr,
    const float* __restrict__ tab, const float* __restrict__ taWy,
    const float* __restrict__ fcw, const float* __restrict__ fcb,
    float* __restrict__ out)
{
  __shared__ SMC sm;
  const int tid = threadIdx.x;
  const int b0  = blockIdx.x * M;
  const int w   = tid >> 6, l = tid & 63;

  { int r = tid >> 7, j = tid & 127;
    sm.s.lh[r][j] = 0.f; sm.s.lc[r][j] = 0.f; }
  if (tid < NG){ sm.s.sb[tid] = tab[tid]; sm.s.wy[tid] = taWy[tid]; }
  if (tid < HH) sm.s.fcv[tid] = fcw[tid];
  if (tid < M)  sm.s.yp[tid] = X[(size_t)(b0+tid)*SS*DD + (DD-1)];
  if (tid < 256){
    int r = tid >> 5, q = (tid & 31)*4;
    *(float4*)&sm.s.ha[0][r][q] = *(const float4*)(Ha + (size_t)(b0+r)*SS*HH + q);
  }
  __syncthreads();

  for (int t = 0; t < SS; ++t){
    // ---- A-frag build (512 thr) + ha(t+1) prefetch (256 thr) ----
    if (tid < 512){
      const float (*haC)[HH] = sm.s.ha[t & 1];
      const int kt = tid >> 6, lf = tid & 63;
      const int row = lf & 15, kg = lf >> 4;
      unsigned hh[4], lw[4];
      if (row < 8){
        const int kb = kt*32 + kg*8;
#pragma unroll
        for (int jp = 0; jp < 4; ++jp){
          int k0 = kb + jp*2;
          float v0 = (k0   < HH) ? sm.s.lh[row][k0]   : haC[row][k0-HH];
          float v1 = (k0+1 < HH) ? sm.s.lh[row][k0+1] : haC[row][k0+1-HH];
          unsigned short h0 = bf16rne(v0), h1 = bf16rne(v1);
          unsigned short l0 = bf16rne(v0 - bfval(h0)), l1 = bf16rne(v1 - bfval(h1));
          hh[jp] = (unsigned)h0 | ((unsigned)h1 << 16);
          lw[jp] = (unsigned)l0 | ((unsigned)l1 << 16);
        }
      } else {
#pragma unroll
        for (int jp = 0; jp < 4; ++jp){ hh[jp] = 0u; lw[jp] = 0u; }
      }
      sm.s.afh[kt*64 + lf] = make_uint4(hh[0], hh[1], hh[2], hh[3]);
      sm.s.afl[kt*64 + lf] = make_uint4(lw[0], lw[1], lw[2], lw[3]);
    } else if (tid < 768 && t + 1 < SS){
      int q = tid - 512;
      int pr = q >> 5, pq = (q & 31)*4;
      *(float4*)&sm.s.ha[(t+1) & 1][pr][pq] =
        *(const float4*)(Ha + (size_t)(b0+pr)*SS*HH + (size_t)(t+1)*HH + pq);
    }
    __syncthreads();

    // ---- MFMA gates: [16x256]@[256x512] + tab + yp*taWy, 16 waves x 2 n-tiles ----
    {
      f32x4 zero4 = {0.f, 0.f, 0.f, 0.f};
      f32x4 acc[2];
      acc[0] = zero4; acc[1] = zero4;
      const uint4* bh = ((const uint4*)(Fr + B3H_OFF)) + (size_t)(w*2)*8*64 + l;
      const uint4* bl = ((const uint4*)(Fr + B3L_OFF)) + (size_t)(w*2)*8*64 + l;
#pragma unroll
      for (int kt = 0; kt < 8; ++kt){
        bf16x8 vah = as_bf(sm.s.afh[kt*64 + l]);
        bf16x8 val = as_bf(sm.s.afl[kt*64 + l]);
#pragma unroll
        for (int n4 = 0; n4 < 2; ++n4){
          bf16x8 vbh = as_bf(bh[(n4*8 + kt)*64]);
          bf16x8 vbl = as_bf(bl[(n4*8 + kt)*64]);
          acc[n4] = __builtin_amdgcn_mfma_f32_16x16x32_bf16(vah, vbh, acc[n4], 0, 0, 0);
          acc[n4] = __builtin_amdgcn_mfma_f32_16x16x32_bf16(val, vbh, acc[n4], 0, 0, 0);
          acc[n4] = __builtin_amdgcn_mfma_f32_16x16x32_bf16(vah, vbl, acc[n4], 0, 0, 0);
        }
      }
      const int row0 = (l >> 4)*4;
      if (row0 < 8){
        const int colb = w*32 + (l & 15);
#pragma unroll
        for (int n4 = 0; n4 < 2; ++n4){
          int col = colb + n4*16;
          float b = sm.s.sb[col];
          float wv = sm.s.wy[col];
#pragma unroll
          for (int j = 0; j < 4; ++j)
            sm.s.g[row0+j][col] = acc[n4][j] + b + sm.s.yp[row0+j]*wv;
        }
      }
    }
    __syncthreads();

    // ---- LSTM pointwise (1 elem/thread) ----
    {
      int r = tid >> 7, j = tid & 127;
      float iv = sigf (sm.s.g[r][j]);
      float fv = sigf (sm.s.g[r][j +   HH]);
      float gv = tanhx(sm.s.g[r][j + 2*HH]);
      float ov = sigf (sm.s.g[r][j + 3*HH]);
      float cn = fv * sm.s.lc[r][j] + iv * gv;
      float hn = ov * tanhx(cn);
      sm.s.lc[r][j] = cn; sm.s.lh[r][j] = hn;
    }
    __syncthreads();

    // ---- y = lh @ fc_w^T + fc_b (waves 0..7) ----
    if (tid < 512){
      const int r = tid >> 6, lx = tid & 63;
      float p = sm.s.lh[r][lx]*sm.s.fcv[lx] + sm.s.lh[r][lx+64]*sm.s.fcv[lx+64];
      p = wsum64(p);
      if (lx == 0) sm.s.yp[r] = p + fcb[0];
    }
    __syncthreads();
  }

  if (tid < M) out[b0 + tid] = sm.s.yp[tid];
}

// ================= Fallback (round-3 VALU kernels, if ws too small) ===============
struct FSM1 {
  float x[M][DD]; float h[M][HH]; float c[M][HH];
  float a[M][DD]; float xw[M][DD]; float g[M][NG];
};
struct FP1 { FSM1 s; float red[8][512]; };
union __align__(16) FSMA { FP1 p1; P2 p2; float pad[21504]; };

__global__ __launch_bounds__(NTF, 2) void fb_ph12_kernel(
    const float* __restrict__ X,
    const float* __restrict__ saW,  const float* __restrict__ saU,  const float* __restrict__ sab,
    const float* __restrict__ saWa, const float* __restrict__ saUa, const float* __restrict__ saba,
    const float* __restrict__ saVa,
    const float* __restrict__ taWa, const float* __restrict__ taba, const float* __restrict__ taVa,
    float* __restrict__ out, float* __restrict__ Hws)
{
  __shared__ FSMA sm;
  const int tid = threadIdx.x;
  const int b0  = blockIdx.x * M;
  const int w   = tid >> 6, l = tid & 63;

  for (int idx = tid; idx < M*HH; idx += NTF){
    int r = idx >> 7, j = idx & 127;
    sm.p1.s.h[r][j] = 0.f; sm.p1.s.c[r][j] = 0.f;
  }
  { int r = tid >> 6, d = tid & 63;
    sm.p1.s.x[r][d] = X[(size_t)(b0+r)*SS*DD + d]; }
  __syncthreads();

  for (int t = 0; t < SS; ++t){
    {
      float pr[M];
#pragma unroll
      for (int r = 0; r < M; ++r) pr[r] = 0.f;
      { const int kb = w*8;
#pragma unroll
        for (int q = 0; q < 2; ++q){
          const int k = kb + q*4;
          const float* wp = saWa + (size_t)k*DD + l;
          float w0 = wp[0], w1 = wp[DD], w2 = wp[2*DD], w3 = wp[3*DD];
#pragma unroll
          for (int r = 0; r < M; ++r){
            float4 v = *(const float4*)&sm.p1.s.x[r][k];
            pr[r] += w0*v.x + w1*v.y + w2*v.z + w3*v.w;
          }
        }
      }
      { const int kb = w*16;
#pragma unroll
        for (int q = 0; q < 4; ++q){
          const int k = kb + q*4;
          const float* wp = saUa + (size_t)k*DD + l;
          float w0 = wp[0], w1 = wp[DD], w2 = wp[2*DD], w3 = wp[3*DD];
#pragma unroll
          for (int r = 0; r < M; ++r){
            float4 v = *(const float4*)&sm.p1.s.h[r][k];
            pr[r] += w0*v.x + w1*v.y + w2*v.z + w3*v.w;
          }
        }
      }
      { const int kb = w*16;
#pragma unroll
        for (int q = 0; q < 4; ++q){
          const int k = kb + q*4;
          const float* wp = saUa + (size_t)(HH + k)*DD + l;
          float w0 = wp[0], w1 = wp[DD], w2 = wp[2*DD], w3 = wp[3*DD];
#pragma unroll
          for (int r = 0; r < M; ++r){
            float4 v = *(const float4*)&sm.p1.s.c[r][k];
            pr[r] += w0*v.x + w1*v.y + w2*v.z + w3*v.w;
          }
        }
      }
#pragma unroll
      for (int r = 0; r < M; ++r) sm.p1.red[w][r*64 + l] = pr[r];
    }
    __syncthreads();
    {
      float s = saba[l];
#pragma unroll
      for (int u = 0; u < 8; ++u) s += sm.p1.red[u][w*64 + l];
      sm.p1.s.a[w][l] = tanhx(s);
    }
    __syncthreads();
    {
      float pr[M];
#pragma unroll
      for (int r = 0; r < M; ++r) pr[r] = 0.f;
      const int kb = w*8;
#pragma unroll
      for (int q = 0; q < 2; ++q){
        const int k = kb + q*4;
        const float* wp = saVa + (size_t)k*DD + l;
        float w0 = wp[0], w1 = wp[DD], w2 = wp[2*DD], w3 = wp[3*DD];
#pragma unroll
        for (int r = 0; r < M; ++r){
          float4 v = *(const float4*)&sm.p1.s.a[r][k];
          pr[r] += w0*v.x + w1*v.y + w2*v.z + w3*v.w;
        }
      }
#pragma unroll
      for (int r = 0; r < M; ++r) sm.p1.red[w][r*64 + l] = pr[r];
    }
    __syncthreads();
    {
      float s = 0.f;
#pragma unroll
      for (int u = 0; u < 8; ++u) s += sm.p1.red[u][w*64 + l];
      float mm = wmax64(s);
      float e  = __expf(s - mm);
      float al = e * (1.0f / wsum64(e));
      out[A_OFF + (size_t)t*BB*DD + (size_t)(b0+w)*DD + l] = al;
      sm.p1.s.xw[w][l] = al * sm.p1.s.x[w][l];
    }
    __syncthreads();
    {
      const int c0 = tid;
      float acc[M];
      const float bv = sab[c0];
#pragma unroll
      for (int r = 0; r < M; ++r) acc[r] = bv;
      for (int k = 0; k < DD; k += 4){
        const float* wp = saW + (size_t)k*NG + c0;
        float w0 = wp[0], w1 = wp[NG], w2 = wp[2*NG], w3 = wp[3*NG];
#pragma unroll
        for (int r = 0; r < M; ++r){
          float4 v = *(const float4*)&sm.p1.s.xw[r][k];
          acc[r] += w0*v.x + w1*v.y + w2*v.z + w3*v.w;
        }
      }
      for (int k = 0; k < HH; k += 4){
        const float* wp = saU + (size_t)k*NG + c0;
        float w0 = wp[0], w1 = wp[NG], w2 = wp[2*NG], w3 = wp[3*NG];
#pragma unroll
        for (int r = 0; r < M; ++r){
          float4 v = *(const float4*)&sm.p1.s.h[r][k];
          acc[r] += w0*v.x + w1*v.y + w2*v.z + w3*v.w;
        }
      }
#pragma unroll
      for (int r = 0; r < M; ++r) sm.p1.s.g[r][c0] = acc[r];
    }
    __syncthreads();
    for (int idx = tid; idx < M*HH; idx += NTF){
      int r = idx >> 7, j = idx & 127;
      float iv = sigf (sm.p1.s.g[r][j]);
      float fv = sigf (sm.p1.s.g[r][j +   HH]);
      float gv = tanhx(sm.p1.s.g[r][j + 2*HH]);
      float ov = sigf (sm.p1.s.g[r][j + 3*HH]);
      float cn = fv * sm.p1.s.c[r][j] + iv * gv;
      float hn = ov * tanhx(cn);
      sm.p1.s.c[r][j] = cn; sm.p1.s.h[r][j] = hn;
      Hws[(size_t)(b0+r)*SS*HH + (size_t)t*HH + j] = hn;
    }
    if (t + 1 < SS){
      int r = tid >> 6, d = tid & 63;
      sm.p1.s.x[r][d] = X[(size_t)(b0+r)*SS*DD + (size_t)(t+1)*DD + d];
    }
    __syncthreads();
  }

  for (int r = 0; r < M; ++r){
    float* Hrow = Hws + (size_t)(b0+r)*SS*HH;
    const int c  = tid & 127;
    const int th = tid >> 7;
    float hacc[32];
#pragma unroll
    for (int i = 0; i < 32; ++i) hacc[i] = 0.f;
#pragma unroll
    for (int ch = 0; ch < 4; ++ch){
      for (int idx = tid; idx < 32*HH/4; idx += NTF)
        ((float4*)sm.p2.A)[idx] = ((const float4*)(Hrow + (size_t)ch*32*HH))[idx];
      __syncthreads();
      { float acc[8];
        const float bv = taba[c];
#pragma unroll
        for (int i = 0; i < 8; ++i) acc[i] = bv;
        for (int k = 0; k < HH; k += 4){
          const float* wp = taWa + (size_t)k*SS + c;
          float w0 = wp[0], w1 = wp[SS], w2 = wp[2*SS], w3 = wp[3*SS];
#pragma unroll
          for (int i = 0; i < 8; ++i){
            float4 v = *(const float4*)&sm.p2.A[th*8+i][k];
            acc[i] += w0*v.x + w1*v.y + w2*v.z + w3*v.w;
          }
        }
#pragma unroll
        for (int i = 0; i < 8; ++i) sm.p2.tmp[th*8+i][c] = tanhx(acc[i]);
      }
      __syncthreads();
      { float acc[8];
#pragma unroll
        for (int i = 0; i < 8; ++i) acc[i] = 0.f;
        for (int k = 0; k < SS; k += 4){
          const float* wp = taVa + (size_t)k*SS + c;
          float w0 = wp[0], w1 = wp[SS], w2 = wp[2*SS], w3 = wp[3*SS];
#pragma unroll
          for (int i = 0; i < 8; ++i){
            float4 v = *(const float4*)&sm.p2.tmp[th*8+i][k];
            acc[i] += w0*v.x + w1*v.y + w2*v.z + w3*v.w;
          }
        }
#pragma unroll
        for (int i = 0; i < 8; ++i) sm.p2.bp[th*8+i][c] = acc[i];
      }
      __syncthreads();
      { const int wv = tid >> 6, lane = tid & 63;
#pragma unroll
        for (int it = 0; it < 4; ++it){
          int tl = wv + 8*it;
          float v0 = sm.p2.bp[tl][lane], v1 = sm.p2.bp[tl][lane+64];
          float mm = wmax64(fmaxf(v0, v1));
          float e0 = __expf(v0 - mm), e1 = __expf(v1 - mm);
          float inv = 1.0f / wsum64(e0 + e1);
          e0 *= inv; e1 *= inv;
          size_t bo = BETA_OFF + (size_t)(ch*32+tl)*BB*SS + (size_t)(b0+r)*SS;
          out[bo + lane]      = e0;
          out[bo + lane + 64] = e1;
          sm.p2.bp[tl][lane]      = e0;
          sm.p2.bp[tl][lane + 64] = e1;
        }
      }
      __syncthreads();
      for (int k = 0; k < SS; k += 4){
        const float* hp = Hrow + (size_t)k*HH + c;
        float hv0 = hp[0], hv1 = hp[HH], hv2 = hp[2*HH], hv3 = hp[3*HH];
#pragma unroll
        for (int i = 0; i < 8; ++i){
          float4 bv = *(const float4*)&sm.p2.bp[th*8+i][k];
          hacc[ch*8+i] += bv.x*hv0 + bv.y*hv1 + bv.z*hv2 + bv.w*hv3;
        }
      }
    }
    __syncthreads();
#pragma unroll
    for (int ch = 0; ch < 4; ++ch)
#pragma unroll
      for (int i = 0; i < 8; ++i)
        Hrow[(size_t)(ch*32 + th*8 + i)*HH + c] = hacc[ch*8+i];
    __syncthreads();
  }
}

__global__ __launch_bounds__(NTF, 2) void fb_ph3_kernel(
    const float* __restrict__ X, const float* __restrict__ Ha,
    const float* __restrict__ taW, const float* __restrict__ taU,
    const float* __restrict__ tab, const float* __restrict__ taWy,
    const float* __restrict__ fcw, const float* __restrict__ fcb,
    float* __restrict__ out)
{
  __shared__ struct {
    float ha[M][HH]; float lh[M][HH]; float lc[M][HH];
    float g[M][NG];  float yp[M];
  } s;
  const int tid = threadIdx.x;
  const int b0  = blockIdx.x * M;

  for (int idx = tid; idx < M*HH; idx += NTF){
    int r = idx >> 7, j = idx & 127;
    s.lh[r][j] = 0.f; s.lc[r][j] = 0.f;
  }
  if (tid < M) s.yp[tid] = X[(size_t)(b0+tid)*SS*DD + (DD-1)];
  if (tid < M*HH/4){
    int r = tid >> 5, q = tid & 31;
    ((float4*)s.ha)[tid] = *(const float4*)(Ha + (size_t)(b0+r)*SS*HH + q*4);
  }
  __syncthreads();

  for (int t = 0; t < SS; ++t){
    {
      const int c0 = tid;
      const float wy = taWy[c0];
      const float tb = tab[c0];
      float acc[M];
#pragma unroll
      for (int r = 0; r < M; ++r) acc[r] = tb + s.yp[r]*wy;
      for (int k = 0; k < HH; k += 4){
        const float* wp = taW + (size_t)k*NG + c0;
        float a0 = wp[0], a1 = wp[NG], a2 = wp[2*NG], a3 = wp[3*NG];
#pragma unroll
        for (int r = 0; r < M; ++r){
          float4 v = *(const float4*)&s.ha[r][k];
          acc[r] += a0*v.x + a1*v.y + a2*v.z + a3*v.w;
        }
      }
      for (int k = 0; k < HH; k += 4){
        const float* wp = taU + (size_t)k*NG + c0;
        float a0 = wp[0], a1 = wp[NG], a2 = wp[2*NG], a3 = wp[3*NG];
#pragma unroll
        for (int r = 0; r < M; ++r){
          float4 v = *(const float4*)&s.lh[r][k];
          acc[r] += a0*v.x + a1*v.y + a2*v.z + a3*v.w;
        }
      }
#pragma unroll
      for (int r = 0; r < M; ++r) s.g[r][c0] = acc[r];
    }
    __syncthreads();
    for (int idx = tid; idx < M*HH; idx += NTF){
      int r = idx >> 7, j = idx & 127;
      float iv = sigf (s.g[r][j]);
      float fv = sigf (s.g[r][j +   HH]);
      float gv = tanhx(s.g[r][j + 2*HH]);
      float ov = sigf (s.g[r][j + 3*HH]);
      float cn = fv * s.lc[r][j] + iv * gv;
      float hn = ov * tanhx(cn);
      s.lc[r][j] = cn; s.lh[r][j] = hn;
    }
    if (t + 1 < SS && tid < M*HH/4){
      int r = tid >> 5, q = tid & 31;
      ((float4*)s.ha)[tid] =
        *(const float4*)(Ha + (size_t)(b0+r)*SS*HH + (size_t)(t+1)*HH + q*4);
    }
    __syncthreads();
    {
      const int r = tid >> 6, lx = tid & 63;
      float p = s.lh[r][lx]*fcw[lx] + s.lh[r][lx+64]*fcw[lx+64];
      p = wsum64(p);
      if (lx == 0) s.yp[r] = p + fcb[0];
    }
    __syncthreads();
  }
  if (tid < M) out[b0 + tid] = s.yp[tid];
}

extern "C" void kernel_launch(void* const* d_in, const int* in_sizes, int n_in,
                              void* d_out, int out_size, void* d_ws, size_t ws_size,
                              hipStream_t stream) {
  (void)in_sizes; (void)n_in; (void)out_size;
  const float* X    = (const float*)d_in[0];
  const float* saW  = (const float*)d_in[1];
  const float* saU  = (const float*)d_in[2];
  const float* sab  = (const float*)d_in[3];
  const float* saWa = (const float*)d_in[4];
  const float* saUa = (const float*)d_in[5];
  const float* saba = (const float*)d_in[6];
  const float* saVa = (const float*)d_in[7];
  const float* taWa = (const float*)d_in[8];
  // d_in[9] = ta_Ua: unused by the reference forward pass
  const float* taba = (const float*)d_in[10];
  const float* taVa = (const float*)d_in[11];
  const float* taW  = (const float*)d_in[12];
  const float* taU  = (const float*)d_in[13];
  const float* tab  = (const float*)d_in[14];
  const float* taWy = (const float*)d_in[15];
  const float* fcw  = (const float*)d_in[16];
  const float* fcb  = (const float*)d_in[17];
  float* out = (float*)d_out;

  if (ws_size >= NEED_BYTES){
    unsigned short* Fr = (unsigned short*)d_ws;
    float* Hws = (float*)((char*)d_ws + FRAG_BYTES);
    hipLaunchKernelGGL(repack_kernel, dim3(512), dim3(256), 0, stream,
                       saW, saU, taU, taW, Fr);
    hipLaunchKernelGGL(mf_ph12_kernel, dim3(BB / M), dim3(NT), 0, stream,
                       X, sab, saWa, saUa, saba, saVa, taWa, taba, taVa,
                       Fr, out, Hws);
    hipLaunchKernelGGL(mf_ph3_kernel, dim3(BB / M), dim3(NT), 0, stream,
                       X, Hws, Fr, tab, taWy, fcw, fcb, out);
  } else {
    float* Hws = (float*)d_ws;
    hipLaunchKernelGGL(fb_ph12_kernel, dim3(BB / M), dim3(NTF), 0, stream,
                       X, saW, saU, sab, saWa, saUa, saba, saVa,
                       taWa, taba, taVa, out, Hws);
    hipLaunchKernelGGL(fb_ph3_kernel, dim3(BB / M), dim3(NTF), 0, stream,
                       X, Hws, taW, taU, tab, taWy, fcw, fcb, out);
  }
}

// Round 8
// 2436.100 us; speedup vs baseline: 1.8176x; 1.8176x over previous
//
#include <hip/hip_runtime.h>

// STA-LSTM forward: B=2048, S=128, D=64, H1=H2=128, OUT=1
// Round 8: phase 2 extracted into its own 2048-block MFMA kernel (plain bf16).
//   repack_kernel: gate weights -> split-bf16 B-frags; taWa/taVa -> bf16 B-frags
//   mf_ph1  (256 blk x 512 thr, 1 blk/CU): spatial-attn LSTM, H -> ws
//   ph2_kernel (2048 blk x 512 thr, 1 blk/CU, ~99KB LDS): betas + h_att, all MFMA
//   mf_ph3  (256 blk x 512 thr): temporal LSTM, K=256 split-bf16 MFMA
//   Fallback to round-3 VALU kernels if ws too small.
// NOTE: NT=512 + __launch_bounds__(512,2) is the ONLY config that reliably gives
// 128 VGPR with no spill (rounds 4/7: NT=1024 variants spill at VGPR=64).

#define BB 2048
#define SS 128
#define DD 64
#define HH 128
#define NG 512
#define M  8
#define NT 512

#define A_OFF    ((size_t)BB)
#define BETA_OFF ((size_t)BB + (size_t)SS*BB*DD)
#define H_BYTES  ((size_t)BB*SS*HH*4)

// fragment buffer layout in ws (ushort offsets)
#define B1_ELEMS (192*512)
#define B3_ELEMS (256*512)
#define BW_ELEMS (128*128)
#define B1H_OFF 0
#define B1L_OFF (B1_ELEMS)
#define B3H_OFF (2*B1_ELEMS)
#define B3L_OFF (2*B1_ELEMS + B3_ELEMS)
#define RW_OFF  (2*B1_ELEMS + 2*B3_ELEMS)
#define RV_OFF  (RW_OFF + BW_ELEMS)
#define FRAG_BYTES ((size_t)(RV_OFF + BW_ELEMS)*2)
#define NEED_BYTES (FRAG_BYTES + H_BYTES)

typedef float f32x4 __attribute__((ext_vector_type(4)));
typedef __bf16 bf16x8 __attribute__((ext_vector_type(8)));
union FB { uint4 u; bf16x8 v; };
__device__ __forceinline__ bf16x8 as_bf(uint4 u){ FB x; x.u = u; return x.v; }

__device__ __forceinline__ unsigned short bf16rne(float f){
  unsigned u = __float_as_uint(f);
  u = (u + 0x7FFFu + ((u >> 16) & 1u)) >> 16;
  return (unsigned short)u;
}
__device__ __forceinline__ float bfval(unsigned short h){
  return __uint_as_float(((unsigned)h) << 16);
}

__device__ __forceinline__ float sigf(float x){ return 1.0f/(1.0f + __expf(-x)); }
__device__ __forceinline__ float tanhx(float x){ return 1.0f - 2.0f/(1.0f + __expf(2.0f*x)); }

__device__ __forceinline__ float wmax64(float v){
#pragma unroll
  for (int m = 32; m; m >>= 1) v = fmaxf(v, __shfl_xor(v, m, 64));
  return v;
}
__device__ __forceinline__ float wsum64(float v){
#pragma unroll
  for (int m = 32; m; m >>= 1) v += __shfl_xor(v, m, 64);
  return v;
}

// ================= repack: weights -> fragment-ordered buffers =================
// B1: K=192 ([saW;saU]) split-bf16.  B3: K=256 ([taU;taW]) split-bf16.
// RW/RV: taWa/taVa (128x128) plain bf16 B-frags for ph2.
__global__ __launch_bounds__(256) void repack_kernel(
    const float* __restrict__ saW, const float* __restrict__ saU,
    const float* __restrict__ taU, const float* __restrict__ taW,
    const float* __restrict__ taWa, const float* __restrict__ taVa,
    unsigned short* __restrict__ F)
{
  int id = blockIdx.x*256 + threadIdx.x;
  if (id < B1_ELEMS){
    int k = id >> 9, n = id & 511;
    float v = (k < DD) ? saW[(size_t)k*NG + n] : saU[(size_t)(k-DD)*NG + n];
    int kt = k >> 5, kw = k & 31, nt = n >> 4, nc = n & 15;
    int lane = ((kw >> 3) << 4) | nc, j = kw & 7;
    size_t off = ((size_t)(nt*6 + kt)*64 + lane)*8 + j;
    unsigned short hi = bf16rne(v);
    unsigned short lo = bf16rne(v - bfval(hi));
    F[B1H_OFF + off] = hi; F[B1L_OFF + off] = lo;
  }
  if (id < B3_ELEMS){
    int k = id >> 9, n = id & 511;
    float v = (k < HH) ? taU[(size_t)k*NG + n] : taW[(size_t)(k-HH)*NG + n];
    int kt = k >> 5, kw = k & 31, nt = n >> 4, nc = n & 15;
    int lane = ((kw >> 3) << 4) | nc, j = kw & 7;
    size_t off = ((size_t)(nt*8 + kt)*64 + lane)*8 + j;
    unsigned short hi = bf16rne(v);
    unsigned short lo = bf16rne(v - bfval(hi));
    F[B3H_OFF + off] = hi; F[B3L_OFF + off] = lo;
  }
  if (id < BW_ELEMS){
    int k = id >> 7, n = id & 127;
    int kt = k >> 5, kw = k & 31, nt = n >> 4, nc = n & 15;
    int lane = ((kw >> 3) << 4) | nc, j = kw & 7;
    size_t off = ((size_t)(nt*4 + kt)*64 + lane)*8 + j;
    F[RW_OFF + off] = bf16rne(taWa[(size_t)k*SS + n]);
    F[RV_OFF + off] = bf16rne(taVa[(size_t)k*SS + n]);
  }
}

// ================= mf_ph1: spatial-attn LSTM (MFMA gates) =================
struct P1 {
  float x[M][DD];      // 2K
  float a[M][DD];      // 2K
  float h[M][HH];      // 4K
  float c[M][HH];      // 4K
  float xw[M][DD];     // 2K
  float g[M][NG];      // 16K
  float red[8][512];   // 16K
  float sbias[NG];     // 2K
  uint4 afh[6*64];     // 6K
  uint4 afl[6*64];     // 6K  -> 60K
};
struct P2 { float A[32][HH]; float tmp[32][SS]; float bp[32][SS]; };  // fallback only
union __align__(16) SMA { P1 p1; float pad[21504]; };   // 84K -> 1 blk/CU

__global__ __launch_bounds__(NT, 2) void mf_ph1_kernel(
    const float* __restrict__ X,   const float* __restrict__ sab,
    const float* __restrict__ saWa, const float* __restrict__ saUa,
    const float* __restrict__ saba, const float* __restrict__ saVa,
    const unsigned short* __restrict__ Fr,
    float* __restrict__ out, float* __restrict__ Hws)
{
  __shared__ SMA sm;
  const int tid = threadIdx.x;
  const int b0  = blockIdx.x * M;
  const int w   = tid >> 6, l = tid & 63;

  for (int idx = tid; idx < M*HH; idx += NT){
    int r = idx >> 7, j = idx & 127;
    sm.p1.h[r][j] = 0.f; sm.p1.c[r][j] = 0.f;
  }
  sm.p1.sbias[tid] = sab[tid];
  { int r = tid >> 6, d = tid & 63;
    sm.p1.x[r][d] = X[(size_t)(b0+r)*SS*DD + d]; }
  __syncthreads();

  for (int t = 0; t < SS; ++t){
    // ---- attn GEMM1 partials (wave k-sliced, weights from L2) ----
    {
      float pr[M];
#pragma unroll
      for (int r = 0; r < M; ++r) pr[r] = 0.f;
      { const int kb = w*8;
#pragma unroll
        for (int q = 0; q < 2; ++q){
          const int k = kb + q*4;
          const float* wp = saWa + (size_t)k*DD + l;
          float w0 = wp[0], w1 = wp[DD], w2 = wp[2*DD], w3 = wp[3*DD];
#pragma unroll
          for (int r = 0; r < M; ++r){
            float4 v = *(const float4*)&sm.p1.x[r][k];
            pr[r] += w0*v.x + w1*v.y + w2*v.z + w3*v.w;
          }
        }
      }
      { const int kb = w*16;
#pragma unroll
        for (int q = 0; q < 4; ++q){
          const int k = kb + q*4;
          const float* wp = saUa + (size_t)k*DD + l;
          float w0 = wp[0], w1 = wp[DD], w2 = wp[2*DD], w3 = wp[3*DD];
#pragma unroll
          for (int r = 0; r < M; ++r){
            float4 v = *(const float4*)&sm.p1.h[r][k];
            pr[r] += w0*v.x + w1*v.y + w2*v.z + w3*v.w;
          }
        }
      }
      { const int kb = w*16;
#pragma unroll
        for (int q = 0; q < 4; ++q){
          const int k = kb + q*4;
          const float* wp = saUa + (size_t)(HH + k)*DD + l;
          float w0 = wp[0], w1 = wp[DD], w2 = wp[2*DD], w3 = wp[3*DD];
#pragma unroll
          for (int r = 0; r < M; ++r){
            float4 v = *(const float4*)&sm.p1.c[r][k];
            pr[r] += w0*v.x + w1*v.y + w2*v.z + w3*v.w;
          }
        }
      }
#pragma unroll
      for (int r = 0; r < M; ++r) sm.p1.red[w][r*64 + l] = pr[r];
    }
    __syncthreads();

    // ---- reduce1 + bias + tanh -> a ----
    {
      const int r = w;
      float s = saba[l];
#pragma unroll
      for (int u = 0; u < 8; ++u) s += sm.p1.red[u][r*64 + l];
      sm.p1.a[r][l] = tanhx(s);
    }
    __syncthreads();

    // ---- attn GEMM2 partials: av = a @ saVa ----
    {
      float pr[M];
#pragma unroll
      for (int r = 0; r < M; ++r) pr[r] = 0.f;
      const int kb = w*8;
#pragma unroll
      for (int q = 0; q < 2; ++q){
        const int k = kb + q*4;
        const float* wp = saVa + (size_t)k*DD + l;
        float w0 = wp[0], w1 = wp[DD], w2 = wp[2*DD], w3 = wp[3*DD];
#pragma unroll
        for (int r = 0; r < M; ++r){
          float4 v = *(const float4*)&sm.p1.a[r][k];
          pr[r] += w0*v.x + w1*v.y + w2*v.z + w3*v.w;
        }
      }
#pragma unroll
      for (int r = 0; r < M; ++r) sm.p1.red[w][r*64 + l] = pr[r];
    }
    __syncthreads();

    // ---- reduce2 + softmax + alphas out + xw ----
    {
      const int r = w;
      float s = 0.f;
#pragma unroll
      for (int u = 0; u < 8; ++u) s += sm.p1.red[u][r*64 + l];
      float mm = wmax64(s);
      float e  = __expf(s - mm);
      float al = e * (1.0f / wsum64(e));
      out[A_OFF + (size_t)t*BB*DD + (size_t)(b0+r)*DD + l] = al;
      sm.p1.xw[r][l] = al * sm.p1.x[r][l];
    }
    __syncthreads();

    // ---- A-frag build (split-bf16, 384 thr) + x(t+1) stage (128 thr) ----
    if (tid < 384){
      const int kt = tid >> 6, lf = tid & 63;
      const int row = lf & 15, kg = lf >> 4;
      unsigned hh[4], lw[4];
      if (row < 8){
        const int kb = kt*32 + kg*8;
#pragma unroll
        for (int jp = 0; jp < 4; ++jp){
          int k0 = kb + jp*2;
          float v0 = (k0   < DD) ? sm.p1.xw[row][k0]   : sm.p1.h[row][k0-DD];
          float v1 = (k0+1 < DD) ? sm.p1.xw[row][k0+1] : sm.p1.h[row][k0+1-DD];
          unsigned short h0 = bf16rne(v0), h1 = bf16rne(v1);
          unsigned short l0 = bf16rne(v0 - bfval(h0)), l1 = bf16rne(v1 - bfval(h1));
          hh[jp] = (unsigned)h0 | ((unsigned)h1 << 16);
          lw[jp] = (unsigned)l0 | ((unsigned)l1 << 16);
        }
      } else {
#pragma unroll
        for (int jp = 0; jp < 4; ++jp){ hh[jp] = 0u; lw[jp] = 0u; }
      }
      sm.p1.afh[kt*64 + lf] = make_uint4(hh[0], hh[1], hh[2], hh[3]);
      sm.p1.afl[kt*64 + lf] = make_uint4(lw[0], lw[1], lw[2], lw[3]);
    } else if (t + 1 < SS){
      int q = tid - 384;
      int r = q >> 4, d0 = (q & 15)*4;
      *(float4*)&sm.p1.x[r][d0] =
        *(const float4*)(X + (size_t)(b0+r)*SS*DD + (size_t)(t+1)*DD + d0);
    }
    __syncthreads();

    // ---- MFMA gates: [16x192] @ [192x512], 3-product split-bf16 ----
    {
      f32x4 zero4 = {0.f, 0.f, 0.f, 0.f};
      f32x4 acc[4];
#pragma unroll
      for (int n4 = 0; n4 < 4; ++n4) acc[n4] = zero4;
      const uint4* bh = ((const uint4*)(Fr + B1H_OFF)) + (size_t)(w*4)*6*64 + l;
      const uint4* bl = ((const uint4*)(Fr + B1L_OFF)) + (size_t)(w*4)*6*64 + l;
#pragma unroll
      for (int kt = 0; kt < 6; ++kt){
        bf16x8 vah = as_bf(sm.p1.afh[kt*64 + l]);
        bf16x8 val = as_bf(sm.p1.afl[kt*64 + l]);
#pragma unroll
        for (int n4 = 0; n4 < 4; ++n4){
          bf16x8 vbh = as_bf(bh[(n4*6 + kt)*64]);
          bf16x8 vbl = as_bf(bl[(n4*6 + kt)*64]);
          acc[n4] = __builtin_amdgcn_mfma_f32_16x16x32_bf16(vah, vbh, acc[n4], 0, 0, 0);
          acc[n4] = __builtin_amdgcn_mfma_f32_16x16x32_bf16(val, vbh, acc[n4], 0, 0, 0);
          acc[n4] = __builtin_amdgcn_mfma_f32_16x16x32_bf16(vah, vbl, acc[n4], 0, 0, 0);
        }
      }
      const int row0 = (l >> 4)*4;
      if (row0 < 8){
        const int colb = w*64 + (l & 15);
#pragma unroll
        for (int n4 = 0; n4 < 4; ++n4){
          int col = colb + n4*16;
          float b = sm.p1.sbias[col];
#pragma unroll
          for (int j = 0; j < 4; ++j) sm.p1.g[row0+j][col] = acc[n4][j] + b;
        }
      }
    }
    __syncthreads();

    // ---- LSTM pointwise + store H ----
    for (int idx = tid; idx < M*HH; idx += NT){
      int r = idx >> 7, j = idx & 127;
      float iv = sigf (sm.p1.g[r][j]);
      float fv = sigf (sm.p1.g[r][j +   HH]);
      float gv = tanhx(sm.p1.g[r][j + 2*HH]);
      float ov = sigf (sm.p1.g[r][j + 3*HH]);
      float cn = fv * sm.p1.c[r][j] + iv * gv;
      float hn = ov * tanhx(cn);
      sm.p1.c[r][j] = cn; sm.p1.h[r][j] = hn;
      Hws[(size_t)(b0+r)*SS*HH + (size_t)t*HH + j] = hn;
    }
    __syncthreads();
  }
}

// ================= ph2_kernel: betas + h_att, all-MFMA, one b per block ===========
struct PH2SM {
  uint4 fA[8][4][64];          // 32 KB: A-frags (H, then tmp, then beta)
  uint4 fB[8][4][64];          // 32 KB: B-frags of H (k=s, n=d)
  unsigned short S[128][136];  // 34 KB: bf16 transpose staging (pad 8 -> no conflicts)
  float bias[SS];              // taba
};

__global__ __launch_bounds__(NT, 2) void ph2_kernel(
    const float* __restrict__ taba, const unsigned short* __restrict__ Fr,
    float* __restrict__ out, float* __restrict__ Hws)
{
  __shared__ PH2SM sm;
  const int tid = threadIdx.x;
  const int b   = blockIdx.x;
  const int w   = tid >> 6, l = tid & 63;
  const int g   = l >> 4, c0 = l & 15;
  float* Hb = Hws + (size_t)b * SS * HH;

  if (tid < SS) sm.bias[tid] = taba[tid];
  // ---- stage H -> S (bf16), coalesced ----
  {
    const float4* src = (const float4*)Hb;
#pragma unroll
    for (int i = 0; i < 8; ++i){
      int fidx = i*NT + tid;                 // 4096 float4
      float4 v = src[fidx];
      int e0 = fidx*4, row = e0 >> 7, col = e0 & 127;
      sm.S[row][col+0] = bf16rne(v.x);
      sm.S[row][col+1] = bf16rne(v.y);
      sm.S[row][col+2] = bf16rne(v.z);
      sm.S[row][col+3] = bf16rne(v.w);
    }
  }
  __syncthreads();

  // ---- build fA (A-frags of H: row=t, k=h) and fB (B-frags of H: k=s, n=d) ----
#pragma unroll
  for (int i = 0; i < 4; ++i){
    int slot = i*NT + tid;
    int mt = slot >> 8, kt = (slot >> 6) & 3, ll = slot & 63;
    int row = mt*16 + (ll & 15), k0 = kt*32 + (ll >> 4)*8;
    ((uint4*)sm.fA)[slot] = *(const uint4*)&sm.S[row][k0];
  }
#pragma unroll
  for (int i = 0; i < 4; ++i){
    int slot = i*NT + tid;
    int nt = slot >> 8, kt = (slot >> 6) & 3, ll = slot & 63;
    int col = nt*16 + (ll & 15), s0 = kt*32 + (ll >> 4)*8;
    unsigned u[4];
#pragma unroll
    for (int p = 0; p < 4; ++p)
      u[p] = (unsigned)sm.S[s0+2*p][col] | ((unsigned)sm.S[s0+2*p+1][col] << 16);
    ((uint4*)sm.fB)[slot] = make_uint4(u[0], u[1], u[2], u[3]);
  }
  __syncthreads();

  f32x4 acc[8];
  f32x4 zero4 = {0.f, 0.f, 0.f, 0.f};

  // ---- GEMM1: tmp = tanh(H @ taWa + ba); wave w = m-tile w ----
#pragma unroll
  for (int nt = 0; nt < 8; ++nt) acc[nt] = zero4;
  {
    const uint4* BW = (const uint4*)(Fr + RW_OFF);
#pragma unroll
    for (int kt = 0; kt < 4; ++kt){
      bf16x8 a = as_bf(sm.fA[w][kt][l]);
#pragma unroll
      for (int nt = 0; nt < 8; ++nt){
        bf16x8 bv = as_bf(BW[(nt*4 + kt)*64 + l]);
        acc[nt] = __builtin_amdgcn_mfma_f32_16x16x32_bf16(a, bv, acc[nt], 0, 0, 0);
      }
    }
  }
#pragma unroll
  for (int nt = 0; nt < 8; ++nt){
    int col = nt*16 + c0;
    float bv = sm.bias[col];
#pragma unroll
    for (int j = 0; j < 4; ++j)
      sm.S[w*16 + g*4 + j][col] = bf16rne(tanhx(acc[nt][j] + bv));
  }
  __syncthreads();

  // ---- rebuild fA from S (tmp) ----
#pragma unroll
  for (int i = 0; i < 4; ++i){
    int slot = i*NT + tid;
    int mt = slot >> 8, kt = (slot >> 6) & 3, ll = slot & 63;
    int row = mt*16 + (ll & 15), k0 = kt*32 + (ll >> 4)*8;
    ((uint4*)sm.fA)[slot] = *(const uint4*)&sm.S[row][k0];
  }
  __syncthreads();

  // ---- GEMM2: bp = tmp @ taVa ----
#pragma unroll
  for (int nt = 0; nt < 8; ++nt) acc[nt] = zero4;
  {
    const uint4* BV = (const uint4*)(Fr + RV_OFF);
#pragma unroll
    for (int kt = 0; kt < 4; ++kt){
      bf16x8 a = as_bf(sm.fA[w][kt][l]);
#pragma unroll
      for (int nt = 0; nt < 8; ++nt){
        bf16x8 bv = as_bf(BV[(nt*4 + kt)*64 + l]);
        acc[nt] = __builtin_amdgcn_mfma_f32_16x16x32_bf16(a, bv, acc[nt], 0, 0, 0);
      }
    }
  }

  // ---- in-register softmax over cols (row lives in one 16-lane group) ----
#pragma unroll
  for (int j = 0; j < 4; ++j){
    float m = acc[0][j];
#pragma unroll
    for (int nt = 1; nt < 8; ++nt) m = fmaxf(m, acc[nt][j]);
#pragma unroll
    for (int ms = 1; ms < 16; ms <<= 1) m = fmaxf(m, __shfl_xor(m, ms, 64));
    float e[8], s = 0.f;
#pragma unroll
    for (int nt = 0; nt < 8; ++nt){ e[nt] = __expf(acc[nt][j] - m); s += e[nt]; }
#pragma unroll
    for (int ms = 1; ms < 16; ms <<= 1) s += __shfl_xor(s, ms, 64);
    float inv = 1.0f / s;
    int row = w*16 + g*4 + j;
    size_t bo = BETA_OFF + (size_t)row*BB*SS + (size_t)b*SS;
#pragma unroll
    for (int nt = 0; nt < 8; ++nt){
      float bv = e[nt] * inv;
      out[bo + nt*16 + c0] = bv;
      sm.S[row][nt*16 + c0] = bf16rne(bv);
    }
  }
  __syncthreads();

  // ---- rebuild fA from S (beta) ----
#pragma unroll
  for (int i = 0; i < 4; ++i){
    int slot = i*NT + tid;
    int mt = slot >> 8, kt = (slot >> 6) & 3, ll = slot & 63;
    int row = mt*16 + (ll & 15), k0 = kt*32 + (ll >> 4)*8;
    ((uint4*)sm.fA)[slot] = *(const uint4*)&sm.S[row][k0];
  }
  __syncthreads();

  // ---- GEMM3: h_att = beta @ H  (A=beta frags, B=fB) ----
#pragma unroll
  for (int nt = 0; nt < 8; ++nt) acc[nt] = zero4;
#pragma unroll
  for (int kt = 0; kt < 4; ++kt){
    bf16x8 a = as_bf(sm.fA[w][kt][l]);
#pragma unroll
    for (int nt = 0; nt < 8; ++nt){
      bf16x8 bv = as_bf(sm.fB[nt][kt][l]);
      acc[nt] = __builtin_amdgcn_mfma_f32_16x16x32_bf16(a, bv, acc[nt], 0, 0, 0);
    }
  }
  // write h_att fp32 (overwrite H[b])
#pragma unroll
  for (int nt = 0; nt < 8; ++nt){
#pragma unroll
    for (int j = 0; j < 4; ++j)
      Hb[(size_t)(w*16 + g*4 + j)*HH + nt*16 + c0] = acc[nt][j];
  }
}

// ================= mf_ph3: temporal LSTM, K=256 MFMA ([lh;ha]@[taU;taW]) =============
struct P3 {
  float ha[2][M][HH];  // 8K (double-buffered)
  float lh[M][HH];     // 4K
  float lc[M][HH];     // 4K
  float g[M][NG];      // 16K
  float sb[NG];        // 2K (tab)
  float wy[NG];        // 2K (taWy)
  float fcv[HH];       // 0.5K
  float yp[M];
  uint4 afh[8*64];     // 8K
  uint4 afl[8*64];     // 8K
};
union __align__(16) SMC { P3 s; float pad[21504]; };   // 84K -> 1 blk/CU

__global__ __launch_bounds__(NT, 2) void mf_ph3_kernel(
    const float* __restrict__ X, const float* __restrict__ Ha,
    const unsigned short* __restrict__ Fr,
    const float* __restrict__ tab, const float* __restrict__ taWy,
    const float* __restrict__ fcw, const float* __restrict__ fcb,
    float* __restrict__ out)
{
  __shared__ SMC sm;
  const int tid = threadIdx.x;
  const int b0  = blockIdx.x * M;
  const int w   = tid >> 6, l = tid & 63;

  for (int idx = tid; idx < M*HH; idx += NT){
    int r = idx >> 7, j = idx & 127;
    sm.s.lh[r][j] = 0.f; sm.s.lc[r][j] = 0.f;
  }
  sm.s.sb[tid] = tab[tid];
  sm.s.wy[tid] = taWy[tid];
  if (tid < HH) sm.s.fcv[tid] = fcw[tid];
  if (tid < M)  sm.s.yp[tid] = X[(size_t)(b0+tid)*SS*DD + (DD-1)];
  if (tid < 256){
    int r = tid >> 5, q = (tid & 31)*4;
    *(float4*)&sm.s.ha[0][r][q] = *(const float4*)(Ha + (size_t)(b0+r)*SS*HH + q);
  }
  __syncthreads();

  for (int t = 0; t < SS; ++t){
    // ---- A-frag build (512 thr) + ha(t+1) prefetch ----
    {
      const float (*haC)[HH] = sm.s.ha[t & 1];
      float4 pf; int pr = 0, pq = 0;
      const bool dop = (t + 1 < SS) && (tid < 256);
      if (dop){
        pr = tid >> 5; pq = (tid & 31)*4;
        pf = *(const float4*)(Ha + (size_t)(b0+pr)*SS*HH + (size_t)(t+1)*HH + pq);
      }
      const int kt = tid >> 6, lf = tid & 63;
      const int row = lf & 15, kg = lf >> 4;
      unsigned hh[4], lw[4];
      if (row < 8){
        const int kb = kt*32 + kg*8;
#pragma unroll
        for (int jp = 0; jp < 4; ++jp){
          int k0 = kb + jp*2;
          float v0 = (k0   < HH) ? sm.s.lh[row][k0]   : haC[row][k0-HH];
          float v1 = (k0+1 < HH) ? sm.s.lh[row][k0+1] : haC[row][k0+1-HH];
          unsigned short h0 = bf16rne(v0), h1 = bf16rne(v1);
          unsigned short l0 = bf16rne(v0 - bfval(h0)), l1 = bf16rne(v1 - bfval(h1));
          hh[jp] = (unsigned)h0 | ((unsigned)h1 << 16);
          lw[jp] = (unsigned)l0 | ((unsigned)l1 << 16);
        }
      } else {
#pragma unroll
        for (int jp = 0; jp < 4; ++jp){ hh[jp] = 0u; lw[jp] = 0u; }
      }
      sm.s.afh[kt*64 + lf] = make_uint4(hh[0], hh[1], hh[2], hh[3]);
      sm.s.afl[kt*64 + lf] = make_uint4(lw[0], lw[1], lw[2], lw[3]);
      if (dop) *(float4*)&sm.s.ha[(t+1) & 1][pr][pq] = pf;
    }
    __syncthreads();

    // ---- MFMA gates: [16x256] @ [256x512] + tab + yp*taWy ----
    {
      f32x4 zero4 = {0.f, 0.f, 0.f, 0.f};
      f32x4 acc[4];
#pragma unroll
      for (int n4 = 0; n4 < 4; ++n4) acc[n4] = zero4;
      const uint4* bh = ((const uint4*)(Fr + B3H_OFF)) + (size_t)(w*4)*8*64 + l;
      const uint4* bl = ((const uint4*)(Fr + B3L_OFF)) + (size_t)(w*4)*8*64 + l;
#pragma unroll
      for (int kt = 0; kt < 8; ++kt){
        bf16x8 vah = as_bf(sm.s.afh[kt*64 + l]);
        bf16x8 val = as_bf(sm.s.afl[kt*64 + l]);
#pragma unroll
        for (int n4 = 0; n4 < 4; ++n4){
          bf16x8 vbh = as_bf(bh[(n4*8 + kt)*64]);
          bf16x8 vbl = as_bf(bl[(n4*8 + kt)*64]);
          acc[n4] = __builtin_amdgcn_mfma_f32_16x16x32_bf16(vah, vbh, acc[n4], 0, 0, 0);
          acc[n4] = __builtin_amdgcn_mfma_f32_16x16x32_bf16(val, vbh, acc[n4], 0, 0, 0);
          acc[n4] = __builtin_amdgcn_mfma_f32_16x16x32_bf16(vah, vbl, acc[n4], 0, 0, 0);
        }
      }
      const int row0 = (l >> 4)*4;
      if (row0 < 8){
        const int colb = w*64 + (l & 15);
#pragma unroll
        for (int n4 = 0; n4 < 4; ++n4){
          int col = colb + n4*16;
          float b = sm.s.sb[col];
          float wv = sm.s.wy[col];
#pragma unroll
          for (int j = 0; j < 4; ++j)
            sm.s.g[row0+j][col] = acc[n4][j] + b + sm.s.yp[row0+j]*wv;
        }
      }
    }
    __syncthreads();

    // ---- LSTM pointwise ----
    for (int idx = tid; idx < M*HH; idx += NT){
      int r = idx >> 7, j = idx & 127;
      float iv = sigf (sm.s.g[r][j]);
      float fv = sigf (sm.s.g[r][j +   HH]);
      float gv = tanhx(sm.s.g[r][j + 2*HH]);
      float ov = sigf (sm.s.g[r][j + 3*HH]);
      float cn = fv * sm.s.lc[r][j] + iv * gv;
      float hn = ov * tanhx(cn);
      sm.s.lc[r][j] = cn; sm.s.lh[r][j] = hn;
    }
    __syncthreads();

    // ---- y = lh @ fc_w^T + fc_b ----
    {
      const int r = tid >> 6, lx = tid & 63;
      float p = sm.s.lh[r][lx]*sm.s.fcv[lx] + sm.s.lh[r][lx+64]*sm.s.fcv[lx+64];
      p = wsum64(p);
      if (lx == 0) sm.s.yp[r] = p + fcb[0];
    }
    __syncthreads();
  }

  if (tid < M) out[b0 + tid] = sm.s.yp[tid];
}

// ================= Fallback (round-3 VALU kernels, if ws too small) ===============
struct FSM1 {
  float x[M][DD]; float h[M][HH]; float c[M][HH];
  float a[M][DD]; float xw[M][DD]; float g[M][NG];
};
struct FP1 { FSM1 s; float red[8][512]; };
union __align__(16) FSMA { FP1 p1; P2 p2; float pad[21504]; };

__global__ __launch_bounds__(NT, 2) void fb_ph12_kernel(
    const float* __restrict__ X,
    const float* __restrict__ saW,  const float* __restrict__ saU,  const float* __restrict__ sab,
    const float* __restrict__ saWa, const float* __restrict__ saUa, const float* __restrict__ saba,
    const float* __restrict__ saVa,
    const float* __restrict__ taWa, const float* __restrict__ taba, const float* __restrict__ taVa,
    float* __restrict__ out, float* __restrict__ Hws)
{
  __shared__ FSMA sm;
  const int tid = threadIdx.x;
  const int b0  = blockIdx.x * M;
  const int w   = tid >> 6, l = tid & 63;

  for (int idx = tid; idx < M*HH; idx += NT){
    int r = idx >> 7, j = idx & 127;
    sm.p1.s.h[r][j] = 0.f; sm.p1.s.c[r][j] = 0.f;
  }
  { int r = tid >> 6, d = tid & 63;
    sm.p1.s.x[r][d] = X[(size_t)(b0+r)*SS*DD + d]; }
  __syncthreads();

  for (int t = 0; t < SS; ++t){
    {
      float pr[M];
#pragma unroll
      for (int r = 0; r < M; ++r) pr[r] = 0.f;
      { const int kb = w*8;
#pragma unroll
        for (int q = 0; q < 2; ++q){
          const int k = kb + q*4;
          const float* wp = saWa + (size_t)k*DD + l;
          float w0 = wp[0], w1 = wp[DD], w2 = wp[2*DD], w3 = wp[3*DD];
#pragma unroll
          for (int r = 0; r < M; ++r){
            float4 v = *(const float4*)&sm.p1.s.x[r][k];
            pr[r] += w0*v.x + w1*v.y + w2*v.z + w3*v.w;
          }
        }
      }
      { const int kb = w*16;
#pragma unroll
        for (int q = 0; q < 4; ++q){
          const int k = kb + q*4;
          const float* wp = saUa + (size_t)k*DD + l;
          float w0 = wp[0], w1 = wp[DD], w2 = wp[2*DD], w3 = wp[3*DD];
#pragma unroll
          for (int r = 0; r < M; ++r){
            float4 v = *(const float4*)&sm.p1.s.h[r][k];
            pr[r] += w0*v.x + w1*v.y + w2*v.z + w3*v.w;
          }
        }
      }
      { const int kb = w*16;
#pragma unroll
        for (int q = 0; q < 4; ++q){
          const int k = kb + q*4;
          const float* wp = saUa + (size_t)(HH + k)*DD + l;
          float w0 = wp[0], w1 = wp[DD], w2 = wp[2*DD], w3 = wp[3*DD];
#pragma unroll
          for (int r = 0; r < M; ++r){
            float4 v = *(const float4*)&sm.p1.s.c[r][k];
            pr[r] += w0*v.x + w1*v.y + w2*v.z + w3*v.w;
          }
        }
      }
#pragma unroll
      for (int r = 0; r < M; ++r) sm.p1.red[w][r*64 + l] = pr[r];
    }
    __syncthreads();
    {
      float s = saba[l];
#pragma unroll
      for (int u = 0; u < 8; ++u) s += sm.p1.red[u][w*64 + l];
      sm.p1.s.a[w][l] = tanhx(s);
    }
    __syncthreads();
    {
      float pr[M];
#pragma unroll
      for (int r = 0; r < M; ++r) pr[r] = 0.f;
      const int kb = w*8;
#pragma unroll
      for (int q = 0; q < 2; ++q){
        const int k = kb + q*4;
        const float* wp = saVa + (size_t)k*DD + l;
        float w0 = wp[0], w1 = wp[DD], w2 = wp[2*DD], w3 = wp[3*DD];
#pragma unroll
        for (int r = 0; r < M; ++r){
          float4 v = *(const float4*)&sm.p1.s.a[r][k];
          pr[r] += w0*v.x + w1*v.y + w2*v.z + w3*v.w;
        }
      }
#pragma unroll
      for (int r = 0; r < M; ++r) sm.p1.red[w][r*64 + l] = pr[r];
    }
    __syncthreads();
    {
      float s = 0.f;
#pragma unroll
      for (int u = 0; u < 8; ++u) s += sm.p1.red[u][w*64 + l];
      float mm = wmax64(s);
      float e  = __expf(s - mm);
      float al = e * (1.0f / wsum64(e));
      out[A_OFF + (size_t)t*BB*DD + (size_t)(b0+w)*DD + l] = al;
      sm.p1.s.xw[w][l] = al * sm.p1.s.x[w][l];
    }
    __syncthreads();
    {
      const int c0 = tid;
      float acc[M];
      const float bv = sab[c0];
#pragma unroll
      for (int r = 0; r < M; ++r) acc[r] = bv;
      for (int k = 0; k < DD; k += 4){
        const float* wp = saW + (size_t)k*NG + c0;
        float w0 = wp[0], w1 = wp[NG], w2 = wp[2*NG], w3 = wp[3*NG];
#pragma unroll
        for (int r = 0; r < M; ++r){
          float4 v = *(const float4*)&sm.p1.s.xw[r][k];
          acc[r] += w0*v.x + w1*v.y + w2*v.z + w3*v.w;
        }
      }
      for (int k = 0; k < HH; k += 4){
        const float* wp = saU + (size_t)k*NG + c0;
        float w0 = wp[0], w1 = wp[NG], w2 = wp[2*NG], w3 = wp[3*NG];
#pragma unroll
        for (int r = 0; r < M; ++r){
          float4 v = *(const float4*)&sm.p1.s.h[r][k];
          acc[r] += w0*v.x + w1*v.y + w2*v.z + w3*v.w;
        }
      }
#pragma unroll
      for (int r = 0; r < M; ++r) sm.p1.s.g[r][c0] = acc[r];
    }
    __syncthreads();
    for (int idx = tid; idx < M*HH; idx += NT){
      int r = idx >> 7, j = idx & 127;
      float iv = sigf (sm.p1.s.g[r][j]);
      float fv = sigf (sm.p1.s.g[r][j +   HH]);
      float gv = tanhx(sm.p1.s.g[r][j + 2*HH]);
      float ov = sigf (sm.p1.s.g[r][j + 3*HH]);
      float cn = fv * sm.p1.s.c[r][j] + iv * gv;
      float hn = ov * tanhx(cn);
      sm.p1.s.c[r][j] = cn; sm.p1.s.h[r][j] = hn;
      Hws[(size_t)(b0+r)*SS*HH + (size_t)t*HH + j] = hn;
    }
    if (t + 1 < SS){
      int r = tid >> 6, d = tid & 63;
      sm.p1.s.x[r][d] = X[(size_t)(b0+r)*SS*DD + (size_t)(t+1)*DD + d];
    }
    __syncthreads();
  }

  for (int r = 0; r < M; ++r){
    float* Hrow = Hws + (size_t)(b0+r)*SS*HH;
    const int c  = tid & 127;
    const int th = tid >> 7;
    float hacc[32];
#pragma unroll
    for (int i = 0; i < 32; ++i) hacc[i] = 0.f;
#pragma unroll
    for (int ch = 0; ch < 4; ++ch){
      for (int idx = tid; idx < 32*HH/4; idx += NT)
        ((float4*)sm.p2.A)[idx] = ((const float4*)(Hrow + (size_t)ch*32*HH))[idx];
      __syncthreads();
      { float acc[8];
        const float bv = taba[c];
#pragma unroll
        for (int i = 0; i < 8; ++i) acc[i] = bv;
        for (int k = 0; k < HH; k += 4){
          const float* wp = taWa + (size_t)k*SS + c;
          float w0 = wp[0], w1 = wp[SS], w2 = wp[2*SS], w3 = wp[3*SS];
#pragma unroll
          for (int i = 0; i < 8; ++i){
            float4 v = *(const float4*)&sm.p2.A[th*8+i][k];
            acc[i] += w0*v.x + w1*v.y + w2*v.z + w3*v.w;
          }
        }
#pragma unroll
        for (int i = 0; i < 8; ++i) sm.p2.tmp[th*8+i][c] = tanhx(acc[i]);
      }
      __syncthreads();
      { float acc[8];
#pragma unroll
        for (int i = 0; i < 8; ++i) acc[i] = 0.f;
        for (int k = 0; k < SS; k += 4){
          const float* wp = taVa + (size_t)k*SS + c;
          float w0 = wp[0], w1 = wp[SS], w2 = wp[2*SS], w3 = wp[3*SS];
#pragma unroll
          for (int i = 0; i < 8; ++i){
            float4 v = *(const float4*)&sm.p2.tmp[th*8+i][k];
            acc[i] += w0*v.x + w1*v.y + w2*v.z + w3*v.w;
          }
        }
#pragma unroll
        for (int i = 0; i < 8; ++i) sm.p2.bp[th*8+i][c] = acc[i];
      }
      __syncthreads();
      { const int wv = tid >> 6, lane = tid & 63;
#pragma unroll
        for (int it = 0; it < 4; ++it){
          int tl = wv + 8*it;
          float v0 = sm.p2.bp[tl][lane], v1 = sm.p2.bp[tl][lane+64];
          float mm = wmax64(fmaxf(v0, v1));
          float e0 = __expf(v0 - mm), e1 = __expf(v1 - mm);
          float inv = 1.0f / wsum64(e0 + e1);
          e0 *= inv; e1 *= inv;
          size_t bo = BETA_OFF + (size_t)(ch*32+tl)*BB*SS + (size_t)(b0+r)*SS;
          out[bo + lane]      = e0;
          out[bo + lane + 64] = e1;
          sm.p2.bp[tl][lane]      = e0;
          sm.p2.bp[tl][lane + 64] = e1;
        }
      }
      __syncthreads();
      for (int k = 0; k < SS; k += 4){
        const float* hp = Hrow + (size_t)k*HH + c;
        float hv0 = hp[0], hv1 = hp[HH], hv2 = hp[2*HH], hv3 = hp[3*HH];
#pragma unroll
        for (int i = 0; i < 8; ++i){
          float4 bv = *(const float4*)&sm.p2.bp[th*8+i][k];
          hacc[ch*8+i] += bv.x*hv0 + bv.y*hv1 + bv.z*hv2 + bv.w*hv3;
        }
      }
    }
    __syncthreads();
#pragma unroll
    for (int ch = 0; ch < 4; ++ch)
#pragma unroll
      for (int i = 0; i < 8; ++i)
        Hrow[(size_t)(ch*32 + th*8 + i)*HH + c] = hacc[ch*8+i];
    __syncthreads();
  }
}

__global__ __launch_bounds__(NT, 2) void fb_ph3_kernel(
    const float* __restrict__ X, const float* __restrict__ Ha,
    const float* __restrict__ taW, const float* __restrict__ taU,
    const float* __restrict__ tab, const float* __restrict__ taWy,
    const float* __restrict__ fcw, const float* __restrict__ fcb,
    float* __restrict__ out)
{
  __shared__ struct {
    float ha[M][HH]; float lh[M][HH]; float lc[M][HH];
    float g[M][NG];  float yp[M];
  } s;
  const int tid = threadIdx.x;
  const int b0  = blockIdx.x * M;

  for (int idx = tid; idx < M*HH; idx += NT){
    int r = idx >> 7, j = idx & 127;
    s.lh[r][j] = 0.f; s.lc[r][j] = 0.f;
  }
  if (tid < M) s.yp[tid] = X[(size_t)(b0+tid)*SS*DD + (DD-1)];
  if (tid < M*HH/4){
    int r = tid >> 5, q = tid & 31;
    ((float4*)s.ha)[tid] = *(const float4*)(Ha + (size_t)(b0+r)*SS*HH + q*4);
  }
  __syncthreads();

  for (int t = 0; t < SS; ++t){
    {
      const int c0 = tid;
      const float wy = taWy[c0];
      const float tb = tab[c0];
      float acc[M];
#pragma unroll
      for (int r = 0; r < M; ++r) acc[r] = tb + s.yp[r]*wy;
      for (int k = 0; k < HH; k += 4){
        const float* wp = taW + (size_t)k*NG + c0;
        float a0 = wp[0], a1 = wp[NG], a2 = wp[2*NG], a3 = wp[3*NG];
#pragma unroll
        for (int r = 0; r < M; ++r){
          float4 v = *(const float4*)&s.ha[r][k];
          acc[r] += a0*v.x + a1*v.y + a2*v.z + a3*v.w;
        }
      }
      for (int k = 0; k < HH; k += 4){
        const float* wp = taU + (size_t)k*NG + c0;
        float a0 = wp[0], a1 = wp[NG], a2 = wp[2*NG], a3 = wp[3*NG];
#pragma unroll
        for (int r = 0; r < M; ++r){
          float4 v = *(const float4*)&s.lh[r][k];
          acc[r] += a0*v.x + a1*v.y + a2*v.z + a3*v.w;
        }
      }
#pragma unroll
      for (int r = 0; r < M; ++r) s.g[r][c0] = acc[r];
    }
    __syncthreads();
    for (int idx = tid; idx < M*HH; idx += NT){
      int r = idx >> 7, j = idx & 127;
      float iv = sigf (s.g[r][j]);
      float fv = sigf (s.g[r][j +   HH]);
      float gv = tanhx(s.g[r][j + 2*HH]);
      float ov = sigf (s.g[r][j + 3*HH]);
      float cn = fv * s.lc[r][j] + iv * gv;
      float hn = ov * tanhx(cn);
      s.lc[r][j] = cn; s.lh[r][j] = hn;
    }
    if (t + 1 < SS && tid < M*HH/4){
      int r = tid >> 5, q = tid & 31;
      ((float4*)s.ha)[tid] =
        *(const float4*)(Ha + (size_t)(b0+r)*SS*HH + (size_t)(t+1)*HH + q*4);
    }
    __syncthreads();
    {
      const int r = tid >> 6, lx = tid & 63;
      float p = s.lh[r][lx]*fcw[lx] + s.lh[r][lx+64]*fcw[lx+64];
      p = wsum64(p);
      if (lx == 0) s.yp[r] = p + fcb[0];
    }
    __syncthreads();
  }
  if (tid < M) out[b0 + tid] = s.yp[tid];
}

extern "C" void kernel_launch(void* const* d_in, const int* in_sizes, int n_in,
                              void* d_out, int out_size, void* d_ws, size_t ws_size,
                              hipStream_t stream) {
  (void)in_sizes; (void)n_in; (void)out_size;
  const float* X    = (const float*)d_in[0];
  const float* saW  = (const float*)d_in[1];
  const float* saU  = (const float*)d_in[2];
  const float* sab  = (const float*)d_in[3];
  const float* saWa = (const float*)d_in[4];
  const float* saUa = (const float*)d_in[5];
  const float* saba = (const float*)d_in[6];
  const float* saVa = (const float*)d_in[7];
  const float* taWa = (const float*)d_in[8];
  // d_in[9] = ta_Ua: unused by the reference forward pass
  const float* taba = (const float*)d_in[10];
  const float* taVa = (const float*)d_in[11];
  const float* taW  = (const float*)d_in[12];
  const float* taU  = (const float*)d_in[13];
  const float* tab  = (const float*)d_in[14];
  const float* taWy = (const float*)d_in[15];
  const float* fcw  = (const float*)d_in[16];
  const float* fcb  = (const float*)d_in[17];
  float* out = (float*)d_out;

  if (ws_size >= NEED_BYTES){
    unsigned short* Fr = (unsigned short*)d_ws;
    float* Hws = (float*)((char*)d_ws + FRAG_BYTES);
    hipLaunchKernelGGL(repack_kernel, dim3(512), dim3(256), 0, stream,
                       saW, saU, taU, taW, taWa, taVa, Fr);
    hipLaunchKernelGGL(mf_ph1_kernel, dim3(BB / M), dim3(NT), 0, stream,
                       X, sab, saWa, saUa, saba, saVa, Fr, out, Hws);
    hipLaunchKernelGGL(ph2_kernel, dim3(BB), dim3(NT), 0, stream,
                       taba, Fr, out, Hws);
    hipLaunchKernelGGL(mf_ph3_kernel, dim3(BB / M), dim3(NT), 0, stream,
                       X, Hws, Fr, tab, taWy, fcw, fcb, out);
  } else {
    float* Hws = (float*)d_ws;
    hipLaunchKernelGGL(fb_ph12_kernel, dim3(BB / M), dim3(NT), 0, stream,
                       X, saW, saU, sab, saWa, saUa, saba, saVa,
                       taWa, taba, taVa, out, Hws);
    hipLaunchKernelGGL(fb_ph3_kernel, dim3(BB / M), dim3(NT), 0, stream,
                       X, Hws, taW, taU, tab, taWy, fcw, fcb, out);
  }
}

// Round 9
// 1983.662 us; speedup vs baseline: 2.2322x; 1.2281x over previous
//
#include <hip/hip_runtime.h>

// STA-LSTM forward: B=2048, S=128, D=64, H1=H2=128, OUT=1
// Round 9: ph1 fully MFMA (attention GEMMs too); frag builds fused into
//          producer phases (pointwise writes h/c frags, softmax writes xw frags,
//          prefetch writes x frags). 6 barriers/step. ph3: 3 barriers/step.
//   repack: gate/attn/Va/B3 split-bf16 frags + ph2 bf16 frags in ws (~1.06 MB)
//   mf_ph1 (256 blk x 512 thr, 1 blk/CU): spatial-attn LSTM, H -> ws
//   ph2_kernel (2048 blk): betas + h_att, all MFMA (round 8, unchanged)
//   mf_ph3 (256 blk): temporal LSTM, K=256 split-bf16 MFMA
//   Fallback to round-3 VALU kernels if ws too small.
// NOTE: NT=512 + __launch_bounds__(512,2) is the ONLY config that reliably gives
// 128 VGPR with no spill (rounds 4/7: NT=1024 variants spill at VGPR=64).

#define BB 2048
#define SS 128
#define DD 64
#define HH 128
#define NG 512
#define M  8
#define NT 512

#define A_OFF    ((size_t)BB)
#define BETA_OFF ((size_t)BB + (size_t)SS*BB*DD)
#define H_BYTES  ((size_t)BB*SS*HH*4)

// fragment buffer layout in ws (ushort offsets)
// gate B: K=192 ([saU(h) kt0-3 | saW(xw) kt4-5]), N=512
// attn B: K=320 ([saUa_h kt0-3 | saUa_c kt4-7 | saWa(x) kt8-9]), N=64
// Va: 64x64.  B3: K=256 ([taU kt0-3 | taW kt4-7]), N=512.  RW/RV: ph2 bf16.
#define B1G_ELEMS (192*512)
#define B1A_ELEMS (320*64)
#define BVA_ELEMS (64*64)
#define B3_ELEMS  (256*512)
#define BW_ELEMS  (128*128)
#define GH_OFF 0
#define GL_OFF (B1G_ELEMS)
#define AH_OFF (2*B1G_ELEMS)
#define AL_OFF (2*B1G_ELEMS + B1A_ELEMS)
#define VH_OFF (2*B1G_ELEMS + 2*B1A_ELEMS)
#define VL_OFF (VH_OFF + BVA_ELEMS)
#define B3H_OFF (VH_OFF + 2*BVA_ELEMS)
#define B3L_OFF (B3H_OFF + B3_ELEMS)
#define RW_OFF  (B3H_OFF + 2*B3_ELEMS)
#define RV_OFF  (RW_OFF + BW_ELEMS)
#define FRAG_BYTES ((size_t)(RV_OFF + BW_ELEMS)*2)
#define NEED_BYTES (FRAG_BYTES + H_BYTES)

typedef float f32x4 __attribute__((ext_vector_type(4)));
typedef __bf16 bf16x8 __attribute__((ext_vector_type(8)));
union FB { uint4 u; bf16x8 v; };
__device__ __forceinline__ bf16x8 as_bf(uint4 u){ FB x; x.u = u; return x.v; }

__device__ __forceinline__ unsigned short bf16rne(float f){
  unsigned u = __float_as_uint(f);
  u = (u + 0x7FFFu + ((u >> 16) & 1u)) >> 16;
  return (unsigned short)u;
}
__device__ __forceinline__ float bfval(unsigned short h){
  return __uint_as_float(((unsigned)h) << 16);
}

__device__ __forceinline__ float sigf(float x){ return 1.0f/(1.0f + __expf(-x)); }
__device__ __forceinline__ float tanhx(float x){ return 1.0f - 2.0f/(1.0f + __expf(2.0f*x)); }

__device__ __forceinline__ float wmax64(float v){
#pragma unroll
  for (int m = 32; m; m >>= 1) v = fmaxf(v, __shfl_xor(v, m, 64));
  return v;
}
__device__ __forceinline__ float wsum64(float v){
#pragma unroll
  for (int m = 32; m; m >>= 1) v += __shfl_xor(v, m, 64);
  return v;
}

// ================= repack: weights -> fragment-ordered buffers =================
__global__ __launch_bounds__(256) void repack_kernel(
    const float* __restrict__ saW, const float* __restrict__ saU,
    const float* __restrict__ saWa, const float* __restrict__ saUa,
    const float* __restrict__ saVa,
    const float* __restrict__ taU, const float* __restrict__ taW,
    const float* __restrict__ taWa, const float* __restrict__ taVa,
    unsigned short* __restrict__ F)
{
  int id = blockIdx.x*256 + threadIdx.x;
  if (id < B1G_ELEMS){          // gate: k 0-127 = saU(h), 128-191 = saW(xw)
    int k = id >> 9, n = id & 511;
    float v = (k < 128) ? saU[(size_t)k*NG + n] : saW[(size_t)(k-128)*NG + n];
    int kk = k >> 5, kw = k & 31, nt = n >> 4, nc = n & 15;
    int lane = ((kw >> 3) << 4) | nc, j = kw & 7;
    size_t off = ((size_t)(nt*6 + kk)*64 + lane)*8 + j;
    unsigned short hi = bf16rne(v);
    F[GH_OFF + off] = hi; F[GL_OFF + off] = bf16rne(v - bfval(hi));
  }
  if (id < B1A_ELEMS){          // attn: k 0-255 = saUa(h,c), 256-319 = saWa(x)
    int k = id >> 6, n = id & 63;
    float v = (k < 256) ? saUa[(size_t)k*DD + n] : saWa[(size_t)(k-256)*DD + n];
    int kt = k >> 5, kw = k & 31, nt = n >> 4, nc = n & 15;
    int lane = ((kw >> 3) << 4) | nc, j = kw & 7;
    size_t off = ((size_t)(nt*10 + kt)*64 + lane)*8 + j;
    unsigned short hi = bf16rne(v);
    F[AH_OFF + off] = hi; F[AL_OFF + off] = bf16rne(v - bfval(hi));
  }
  if (id < BVA_ELEMS){          // saVa 64x64
    int k = id >> 6, n = id & 63;
    float v = saVa[(size_t)k*DD + n];
    int kt = k >> 5, kw = k & 31, nt = n >> 4, nc = n & 15;
    int lane = ((kw >> 3) << 4) | nc, j = kw & 7;
    size_t off = ((size_t)(nt*2 + kt)*64 + lane)*8 + j;
    unsigned short hi = bf16rne(v);
    F[VH_OFF + off] = hi; F[VL_OFF + off] = bf16rne(v - bfval(hi));
  }
  if (id < B3_ELEMS){           // ph3: k 0-127 = taU(lh), 128-255 = taW(ha)
    int k = id >> 9, n = id & 511;
    float v = (k < HH) ? taU[(size_t)k*NG + n] : taW[(size_t)(k-HH)*NG + n];
    int kt = k >> 5, kw = k & 31, nt = n >> 4, nc = n & 15;
    int lane = ((kw >> 3) << 4) | nc, j = kw & 7;
    size_t off = ((size_t)(nt*8 + kt)*64 + lane)*8 + j;
    unsigned short hi = bf16rne(v);
    F[B3H_OFF + off] = hi; F[B3L_OFF + off] = bf16rne(v - bfval(hi));
  }
  if (id < BW_ELEMS){           // ph2 bf16 frags
    int k = id >> 7, n = id & 127;
    int kt = k >> 5, kw = k & 31, nt = n >> 4, nc = n & 15;
    int lane = ((kw >> 3) << 4) | nc, j = kw & 7;
    size_t off = ((size_t)(nt*4 + kt)*64 + lane)*8 + j;
    F[RW_OFF + off] = bf16rne(taWa[(size_t)k*SS + n]);
    F[RV_OFF + off] = bf16rne(taVa[(size_t)k*SS + n]);
  }
}

// ================= mf_ph1: spatial-attn LSTM, fully MFMA =================
// af tiles: 0-3 h, 4-7 c, 8-9 x (attn A, K=320) ; {0-3 h, 10-11 xw} = gate A (K=192)
struct P1 {
  uint4 afh[12*64];    // 12K
  uint4 afl[12*64];    // 12K
  uint4 aah[2*64];     // 2K (a frags hi)
  uint4 aal[2*64];     // 2K
  float xx[M][DD];     // 2K
  float cc[M][HH];     // 4K
  float red[2][M][64]; // 4K
  float g[M][NG];      // 16K
  float sbias[NG];     // 2K
};
struct P2 { float A[32][HH]; float tmp[32][SS]; float bp[32][SS]; };  // fallback/ph2fb
union __align__(16) SMA { P1 p1; float pad[21504]; };   // 84K -> 1 blk/CU

__global__ __launch_bounds__(NT, 2) void mf_ph1_kernel(
    const float* __restrict__ X,   const float* __restrict__ sab,
    const float* __restrict__ saba,
    const unsigned short* __restrict__ Fr,
    float* __restrict__ out, float* __restrict__ Hws)
{
  __shared__ SMA sm;
  const int tid = threadIdx.x;
  const int b0  = blockIdx.x * M;
  const int w   = tid >> 6, l = tid & 63;

  // ---- init: zero frags & c, stage bias ----
  {
    uint4 z4 = make_uint4(0,0,0,0);
    for (int i = tid; i < 12*64; i += NT){ sm.p1.afh[i] = z4; sm.p1.afl[i] = z4; }
    if (tid < 2*64){ sm.p1.aah[tid] = z4; sm.p1.aal[tid] = z4; }
    for (int i = tid; i < M*HH; i += NT) ((float*)sm.p1.cc)[i] = 0.f;
    sm.p1.sbias[tid] = sab[tid];
  }
  __syncthreads();
  // ---- stage x(0) + x-frags (tiles 8-9) ----
  if (tid < 128){
    int r = tid >> 4, d0 = (tid & 15)*4;
    float4 v = *(const float4*)(X + (size_t)(b0+r)*SS*DD + d0);
    *(float4*)&sm.p1.xx[r][d0] = v;
    unsigned short* AFH = (unsigned short*)sm.p1.afh;
    unsigned short* AFL = (unsigned short*)sm.p1.afl;
    int kt = 8 + (d0 >> 5), lane = (((d0 & 31) >> 3) << 4) | r, jj0 = d0 & 7;
    float vv[4] = {v.x, v.y, v.z, v.w};
#pragma unroll
    for (int p = 0; p < 4; ++p){
      unsigned short h_ = bf16rne(vv[p]);
      AFH[(kt*64 + lane)*8 + jj0 + p] = h_;
      AFL[(kt*64 + lane)*8 + jj0 + p] = bf16rne(vv[p] - bfval(h_));
    }
  }
  __syncthreads();

  for (int t = 0; t < SS; ++t){
    // ---- P1: attn MFMA  a_pre = [h|c|x] @ [saUa;saWa]  (wave: nt=w&3, kh=w>>2) ----
    {
      const int nt = w & 3, kh = w >> 2;
      f32x4 a0 = {0.f,0.f,0.f,0.f}, a1 = {0.f,0.f,0.f,0.f};
      const uint4* BAH = (const uint4*)(Fr + AH_OFF);
      const uint4* BAL = (const uint4*)(Fr + AL_OFF);
#pragma unroll
      for (int q = 0; q < 5; ++q){
        const int kt = kh*5 + q;
        bf16x8 ah = as_bf(sm.p1.afh[kt*64 + l]);
        bf16x8 av = as_bf(sm.p1.afl[kt*64 + l]);
        bf16x8 bh = as_bf(BAH[(nt*10 + kt)*64 + l]);
        bf16x8 bl = as_bf(BAL[(nt*10 + kt)*64 + l]);
        if (q & 1){
          a1 = __builtin_amdgcn_mfma_f32_16x16x32_bf16(ah, bh, a1, 0, 0, 0);
          a1 = __builtin_amdgcn_mfma_f32_16x16x32_bf16(av, bh, a1, 0, 0, 0);
          a1 = __builtin_amdgcn_mfma_f32_16x16x32_bf16(ah, bl, a1, 0, 0, 0);
        } else {
          a0 = __builtin_amdgcn_mfma_f32_16x16x32_bf16(ah, bh, a0, 0, 0, 0);
          a0 = __builtin_amdgcn_mfma_f32_16x16x32_bf16(av, bh, a0, 0, 0, 0);
          a0 = __builtin_amdgcn_mfma_f32_16x16x32_bf16(ah, bl, a0, 0, 0, 0);
        }
      }
      f32x4 acc = a0 + a1;
      const int row0 = (l >> 4)*4, c0 = l & 15;
      if (row0 < 8){
#pragma unroll
        for (int jj = 0; jj < 4; ++jj)
          sm.p1.red[kh][row0+jj][nt*16 + c0] = acc[jj];
      }
    }
    __syncthreads();

    // ---- P2: combine + bias + tanh -> a-frags ----
    {
      const int r = w, col = l;
      float s = sm.p1.red[0][r][col] + sm.p1.red[1][r][col] + saba[col];
      float av = tanhx(s);
      unsigned short h_ = bf16rne(av);
      int kt = col >> 5, lane = (((col & 31) >> 3) << 4) | r, jj = col & 7;
      ((unsigned short*)sm.p1.aah)[(kt*64 + lane)*8 + jj] = h_;
      ((unsigned short*)sm.p1.aal)[(kt*64 + lane)*8 + jj] = bf16rne(av - bfval(h_));
    }
    __syncthreads();

    // ---- P3: GEMM2 MFMA  av = a @ saVa  (wave: nt=w&3, kt=w>>2) ----
    {
      const int nt = w & 3, kt = w >> 2;   // kt 0-1
      f32x4 acc = {0.f,0.f,0.f,0.f};
      bf16x8 ah = as_bf(sm.p1.aah[kt*64 + l]);
      bf16x8 av = as_bf(sm.p1.aal[kt*64 + l]);
      bf16x8 bh = as_bf(((const uint4*)(Fr + VH_OFF))[(nt*2 + kt)*64 + l]);
      bf16x8 bl = as_bf(((const uint4*)(Fr + VL_OFF))[(nt*2 + kt)*64 + l]);
      acc = __builtin_amdgcn_mfma_f32_16x16x32_bf16(ah, bh, acc, 0, 0, 0);
      acc = __builtin_amdgcn_mfma_f32_16x16x32_bf16(av, bh, acc, 0, 0, 0);
      acc = __builtin_amdgcn_mfma_f32_16x16x32_bf16(ah, bl, acc, 0, 0, 0);
      const int row0 = (l >> 4)*4, c0 = l & 15;
      if (row0 < 8){
#pragma unroll
        for (int jj = 0; jj < 4; ++jj)
          sm.p1.red[kt][row0+jj][nt*16 + c0] = acc[jj];
      }
    }
    __syncthreads();

    // ---- P4: softmax + alphas out + xw-frags (tiles 10-11) ----
    {
      const int r = w, col = l;
      float s = sm.p1.red[0][r][col] + sm.p1.red[1][r][col];
      float mm = wmax64(s);
      float e  = __expf(s - mm);
      float alv = e * (1.0f / wsum64(e));
      out[A_OFF + (size_t)t*BB*DD + (size_t)(b0+r)*DD + col] = alv;
      float xwv = alv * sm.p1.xx[r][col];
      unsigned short h_ = bf16rne(xwv);
      int kt = 10 + (col >> 5), lane = (((col & 31) >> 3) << 4) | r, jj = col & 7;
      ((unsigned short*)sm.p1.afh)[(kt*64 + lane)*8 + jj] = h_;
      ((unsigned short*)sm.p1.afl)[(kt*64 + lane)*8 + jj] = bf16rne(xwv - bfval(h_));
    }
    __syncthreads();

    // ---- P5: gates MFMA  [h kt0-3 | xw kt10-11] @ B1g  + x(t+1) prefetch issue ----
    float4 pf;
    const bool dox = (tid < 128) && (t + 1 < SS);
    if (dox){
      int r = tid >> 4, d0 = (tid & 15)*4;
      pf = *(const float4*)(X + (size_t)(b0+r)*SS*DD + (size_t)(t+1)*DD + d0);
    }
    {
      f32x4 zero4 = {0.f,0.f,0.f,0.f};
      f32x4 acc[4];
#pragma unroll
      for (int n4 = 0; n4 < 4; ++n4) acc[n4] = zero4;
      const uint4* GH = (const uint4*)(Fr + GH_OFF);
      const uint4* GL = (const uint4*)(Fr + GL_OFF);
#pragma unroll
      for (int kk = 0; kk < 6; ++kk){
        const int afi = (kk < 4) ? kk : (kk + 6);   // {0,1,2,3,10,11}
        bf16x8 ah = as_bf(sm.p1.afh[afi*64 + l]);
        bf16x8 av = as_bf(sm.p1.afl[afi*64 + l]);
#pragma unroll
        for (int n4 = 0; n4 < 4; ++n4){
          const int ntg = w*4 + n4;
          bf16x8 bh = as_bf(GH[(ntg*6 + kk)*64 + l]);
          bf16x8 bl = as_bf(GL[(ntg*6 + kk)*64 + l]);
          acc[n4] = __builtin_amdgcn_mfma_f32_16x16x32_bf16(ah, bh, acc[n4], 0, 0, 0);
          acc[n4] = __builtin_amdgcn_mfma_f32_16x16x32_bf16(av, bh, acc[n4], 0, 0, 0);
          acc[n4] = __builtin_amdgcn_mfma_f32_16x16x32_bf16(ah, bl, acc[n4], 0, 0, 0);
        }
      }
      const int row0 = (l >> 4)*4, c0 = l & 15;
      if (row0 < 8){
#pragma unroll
        for (int n4 = 0; n4 < 4; ++n4){
          int col = w*64 + n4*16 + c0;
          float b = sm.p1.sbias[col];
#pragma unroll
          for (int jj = 0; jj < 4; ++jj)
            sm.p1.g[row0+jj][col] = acc[n4][jj] + b;
        }
      }
    }
    __syncthreads();

    // ---- P6: pointwise + h/c frag build + H store + x(t+1) commit ----
    {
      unsigned short* AFH = (unsigned short*)sm.p1.afh;
      unsigned short* AFL = (unsigned short*)sm.p1.afl;
#pragma unroll
      for (int h2 = 0; h2 < 2; ++h2){
        int idx = h2*NT + tid;
        int r = idx >> 7, j = idx & 127;
        float iv = sigf (sm.p1.g[r][j]);
        float fv = sigf (sm.p1.g[r][j + 128]);
        float gv = tanhx(sm.p1.g[r][j + 256]);
        float ov = sigf (sm.p1.g[r][j + 384]);
        float cn = fv * sm.p1.cc[r][j] + iv * gv;
        float hn = ov * tanhx(cn);
        sm.p1.cc[r][j] = cn;
        Hws[(size_t)(b0+r)*SS*HH + (size_t)t*HH + j] = hn;
        int lane = (((j & 31) >> 3) << 4) | r, jj = j & 7;
        int ktH = j >> 5, ktC = 4 + (j >> 5);
        unsigned short hh_ = bf16rne(hn);
        unsigned short ch_ = bf16rne(cn);
        AFH[(ktH*64 + lane)*8 + jj] = hh_;
        AFL[(ktH*64 + lane)*8 + jj] = bf16rne(hn - bfval(hh_));
        AFH[(ktC*64 + lane)*8 + jj] = ch_;
        AFL[(ktC*64 + lane)*8 + jj] = bf16rne(cn - bfval(ch_));
      }
      if (dox){
        int r = tid >> 4, d0 = (tid & 15)*4;
        *(float4*)&sm.p1.xx[r][d0] = pf;
        int kt = 8 + (d0 >> 5), lane = (((d0 & 31) >> 3) << 4) | r, jj0 = d0 & 7;
        float vv[4] = {pf.x, pf.y, pf.z, pf.w};
#pragma unroll
        for (int p = 0; p < 4; ++p){
          unsigned short h_ = bf16rne(vv[p]);
          AFH[(kt*64 + lane)*8 + jj0 + p] = h_;
          AFL[(kt*64 + lane)*8 + jj0 + p] = bf16rne(vv[p] - bfval(h_));
        }
      }
    }
    __syncthreads();
  }
}

// ================= ph2_kernel: betas + h_att, all-MFMA (round 8) ===========
struct PH2SM {
  uint4 fA[8][4][64];          // 32 KB
  uint4 fB[8][4][64];          // 32 KB
  unsigned short S[128][136];  // 34 KB (pad 8)
  float bias[SS];
};

__global__ __launch_bounds__(NT, 2) void ph2_kernel(
    const float* __restrict__ taba, const unsigned short* __restrict__ Fr,
    float* __restrict__ out, float* __restrict__ Hws)
{
  __shared__ PH2SM sm;
  const int tid = threadIdx.x;
  const int b   = blockIdx.x;
  const int w   = tid >> 6, l = tid & 63;
  const int g   = l >> 4, c0 = l & 15;
  float* Hb = Hws + (size_t)b * SS * HH;

  if (tid < SS) sm.bias[tid] = taba[tid];
  {
    const float4* src = (const float4*)Hb;
#pragma unroll
    for (int i = 0; i < 8; ++i){
      int fidx = i*NT + tid;
      float4 v = src[fidx];
      int e0 = fidx*4, row = e0 >> 7, col = e0 & 127;
      sm.S[row][col+0] = bf16rne(v.x);
      sm.S[row][col+1] = bf16rne(v.y);
      sm.S[row][col+2] = bf16rne(v.z);
      sm.S[row][col+3] = bf16rne(v.w);
    }
  }
  __syncthreads();

#pragma unroll
  for (int i = 0; i < 4; ++i){
    int slot = i*NT + tid;
    int mt = slot >> 8, kt = (slot >> 6) & 3, ll = slot & 63;
    int row = mt*16 + (ll & 15), k0 = kt*32 + (ll >> 4)*8;
    ((uint4*)sm.fA)[slot] = *(const uint4*)&sm.S[row][k0];
  }
#pragma unroll
  for (int i = 0; i < 4; ++i){
    int slot = i*NT + tid;
    int nt = slot >> 8, kt = (slot >> 6) & 3, ll = slot & 63;
    int col = nt*16 + (ll & 15), s0 = kt*32 + (ll >> 4)*8;
    unsigned u[4];
#pragma unroll
    for (int p = 0; p < 4; ++p)
      u[p] = (unsigned)sm.S[s0+2*p][col] | ((unsigned)sm.S[s0+2*p+1][col] << 16);
    ((uint4*)sm.fB)[slot] = make_uint4(u[0], u[1], u[2], u[3]);
  }
  __syncthreads();

  f32x4 acc[8];
  f32x4 zero4 = {0.f, 0.f, 0.f, 0.f};

#pragma unroll
  for (int nt = 0; nt < 8; ++nt) acc[nt] = zero4;
  {
    const uint4* BW = (const uint4*)(Fr + RW_OFF);
#pragma unroll
    for (int kt = 0; kt < 4; ++kt){
      bf16x8 a = as_bf(sm.fA[w][kt][l]);
#pragma unroll
      for (int nt = 0; nt < 8; ++nt){
        bf16x8 bv = as_bf(BW[(nt*4 + kt)*64 + l]);
        acc[nt] = __builtin_amdgcn_mfma_f32_16x16x32_bf16(a, bv, acc[nt], 0, 0, 0);
      }
    }
  }
#pragma unroll
  for (int nt = 0; nt < 8; ++nt){
    int col = nt*16 + c0;
    float bv = sm.bias[col];
#pragma unroll
    for (int j = 0; j < 4; ++j)
      sm.S[w*16 + g*4 + j][col] = bf16rne(tanhx(acc[nt][j] + bv));
  }
  __syncthreads();

#pragma unroll
  for (int i = 0; i < 4; ++i){
    int slot = i*NT + tid;
    int mt = slot >> 8, kt = (slot >> 6) & 3, ll = slot & 63;
    int row = mt*16 + (ll & 15), k0 = kt*32 + (ll >> 4)*8;
    ((uint4*)sm.fA)[slot] = *(const uint4*)&sm.S[row][k0];
  }
  __syncthreads();

#pragma unroll
  for (int nt = 0; nt < 8; ++nt) acc[nt] = zero4;
  {
    const uint4* BV = (const uint4*)(Fr + RV_OFF);
#pragma unroll
    for (int kt = 0; kt < 4; ++kt){
      bf16x8 a = as_bf(sm.fA[w][kt][l]);
#pragma unroll
      for (int nt = 0; nt < 8; ++nt){
        bf16x8 bv = as_bf(BV[(nt*4 + kt)*64 + l]);
        acc[nt] = __builtin_amdgcn_mfma_f32_16x16x32_bf16(a, bv, acc[nt], 0, 0, 0);
      }
    }
  }

#pragma unroll
  for (int j = 0; j < 4; ++j){
    float m = acc[0][j];
#pragma unroll
    for (int nt = 1; nt < 8; ++nt) m = fmaxf(m, acc[nt][j]);
#pragma unroll
    for (int ms = 1; ms < 16; ms <<= 1) m = fmaxf(m, __shfl_xor(m, ms, 64));
    float e[8], s = 0.f;
#pragma unroll
    for (int nt = 0; nt < 8; ++nt){ e[nt] = __expf(acc[nt][j] - m); s += e[nt]; }
#pragma unroll
    for (int ms = 1; ms < 16; ms <<= 1) s += __shfl_xor(s, ms, 64);
    float inv = 1.0f / s;
    int row = w*16 + g*4 + j;
    size_t bo = BETA_OFF + (size_t)row*BB*SS + (size_t)b*SS;
#pragma unroll
    for (int nt = 0; nt < 8; ++nt){
      float bv = e[nt] * inv;
      out[bo + nt*16 + c0] = bv;
      sm.S[row][nt*16 + c0] = bf16rne(bv);
    }
  }
  __syncthreads();

#pragma unroll
  for (int i = 0; i < 4; ++i){
    int slot = i*NT + tid;
    int mt = slot >> 8, kt = (slot >> 6) & 3, ll = slot & 63;
    int row = mt*16 + (ll & 15), k0 = kt*32 + (ll >> 4)*8;
    ((uint4*)sm.fA)[slot] = *(const uint4*)&sm.S[row][k0];
  }
  __syncthreads();

#pragma unroll
  for (int nt = 0; nt < 8; ++nt) acc[nt] = zero4;
#pragma unroll
  for (int kt = 0; kt < 4; ++kt){
    bf16x8 a = as_bf(sm.fA[w][kt][l]);
#pragma unroll
    for (int nt = 0; nt < 8; ++nt){
      bf16x8 bv = as_bf(sm.fB[nt][kt][l]);
      acc[nt] = __builtin_amdgcn_mfma_f32_16x16x32_bf16(a, bv, acc[nt], 0, 0, 0);
    }
  }
#pragma unroll
  for (int nt = 0; nt < 8; ++nt){
#pragma unroll
    for (int j = 0; j < 4; ++j)
      Hb[(size_t)(w*16 + g*4 + j)*HH + nt*16 + c0] = acc[nt][j];
  }
}

// ================= mf_ph3: temporal LSTM, 3 barriers/step =================
// af3 tiles: 0-3 lh, 4-7 ha
struct P3 {
  uint4 afh[8*64];     // 8K
  uint4 afl[8*64];     // 8K
  float lh[M][HH];     // 4K
  float lc[M][HH];     // 4K
  float g[M][NG];      // 16K
  float sb[NG];        // 2K
  float wy[NG];        // 2K
  float fcv[HH];
  float yp[M];
};
union __align__(16) SMC { P3 s; float pad[21504]; };   // 84K -> 1 blk/CU

__global__ __launch_bounds__(NT, 2) void mf_ph3_kernel(
    const float* __restrict__ X, const float* __restrict__ Ha,
    const unsigned short* __restrict__ Fr,
    const float* __restrict__ tab, const float* __restrict__ taWy,
    const float* __restrict__ fcw, const float* __restrict__ fcb,
    float* __restrict__ out)
{
  __shared__ SMC sm;
  const int tid = threadIdx.x;
  const int b0  = blockIdx.x * M;
  const int w   = tid >> 6, l = tid & 63;

  // ---- init ----
  {
    uint4 z4 = make_uint4(0,0,0,0);
    sm.s.afh[tid] = z4; sm.s.afl[tid] = z4;   // 512 covers 8*64
    for (int i = tid; i < M*HH; i += NT){
      ((float*)sm.s.lh)[i] = 0.f; ((float*)sm.s.lc)[i] = 0.f;
    }
    sm.s.sb[tid] = tab[tid];
    sm.s.wy[tid] = taWy[tid];
    if (tid < HH) sm.s.fcv[tid] = fcw[tid];
    if (tid < M)  sm.s.yp[tid] = X[(size_t)(b0+tid)*SS*DD + (DD-1)];
  }
  __syncthreads();
  // ---- ha(0) frags (tiles 4-7) ----
  if (tid < 256){
    int r = tid >> 5, d0 = (tid & 31)*4;
    float4 v = *(const float4*)(Ha + (size_t)(b0+r)*SS*HH + d0);
    unsigned short* AFH = (unsigned short*)sm.s.afh;
    unsigned short* AFL = (unsigned short*)sm.s.afl;
    int kt = 4 + (d0 >> 5), lane = (((d0 & 31) >> 3) << 4) | r, jj0 = d0 & 7;
    float vv[4] = {v.x, v.y, v.z, v.w};
#pragma unroll
    for (int p = 0; p < 4; ++p){
      unsigned short h_ = bf16rne(vv[p]);
      AFH[(kt*64 + lane)*8 + jj0 + p] = h_;
      AFL[(kt*64 + lane)*8 + jj0 + p] = bf16rne(vv[p] - bfval(h_));
    }
  }
  __syncthreads();

  for (int t = 0; t < SS; ++t){
    // ---- Q1: gates MFMA + ha(t+1) prefetch issue ----
    float4 pf;
    const bool dop = (tid < 256) && (t + 1 < SS);
    if (dop){
      int r = tid >> 5, d0 = (tid & 31)*4;
      pf = *(const float4*)(Ha + (size_t)(b0+r)*SS*HH + (size_t)(t+1)*HH + d0);
    }
    {
      f32x4 zero4 = {0.f,0.f,0.f,0.f};
      f32x4 acc[4];
#pragma unroll
      for (int n4 = 0; n4 < 4; ++n4) acc[n4] = zero4;
      const uint4* BH = (const uint4*)(Fr + B3H_OFF);
      const uint4* BL = (const uint4*)(Fr + B3L_OFF);
#pragma unroll
      for (int kt = 0; kt < 8; ++kt){
        bf16x8 ah = as_bf(sm.s.afh[kt*64 + l]);
        bf16x8 av = as_bf(sm.s.afl[kt*64 + l]);
#pragma unroll
        for (int n4 = 0; n4 < 4; ++n4){
          const int ntg = w*4 + n4;
          bf16x8 bh = as_bf(BH[(ntg*8 + kt)*64 + l]);
          bf16x8 bl = as_bf(BL[(ntg*8 + kt)*64 + l]);
          acc[n4] = __builtin_amdgcn_mfma_f32_16x16x32_bf16(ah, bh, acc[n4], 0, 0, 0);
          acc[n4] = __builtin_amdgcn_mfma_f32_16x16x32_bf16(av, bh, acc[n4], 0, 0, 0);
          acc[n4] = __builtin_amdgcn_mfma_f32_16x16x32_bf16(ah, bl, acc[n4], 0, 0, 0);
        }
      }
      const int row0 = (l >> 4)*4, c0 = l & 15;
      if (row0 < 8){
#pragma unroll
        for (int n4 = 0; n4 < 4; ++n4){
          int col = w*64 + n4*16 + c0;
          float b = sm.s.sb[col];
          float wv = sm.s.wy[col];
#pragma unroll
          for (int jj = 0; jj < 4; ++jj)
            sm.s.g[row0+jj][col] = acc[n4][jj] + b + sm.s.yp[row0+jj]*wv;
        }
      }
    }
    __syncthreads();

    // ---- Q2: pointwise + lh-frag build (tiles 0-3) ----
    {
      unsigned short* AFH = (unsigned short*)sm.s.afh;
      unsigned short* AFL = (unsigned short*)sm.s.afl;
#pragma unroll
      for (int h2 = 0; h2 < 2; ++h2){
        int idx = h2*NT + tid;
        int r = idx >> 7, j = idx & 127;
        float iv = sigf (sm.s.g[r][j]);
        float fv = sigf (sm.s.g[r][j + 128]);
        float gv = tanhx(sm.s.g[r][j + 256]);
        float ov = sigf (sm.s.g[r][j + 384]);
        float cn = fv * sm.s.lc[r][j] + iv * gv;
        float hn = ov * tanhx(cn);
        sm.s.lc[r][j] = cn; sm.s.lh[r][j] = hn;
        int kt = j >> 5, lane = (((j & 31) >> 3) << 4) | r, jj = j & 7;
        unsigned short h_ = bf16rne(hn);
        AFH[(kt*64 + lane)*8 + jj] = h_;
        AFL[(kt*64 + lane)*8 + jj] = bf16rne(hn - bfval(h_));
      }
    }
    __syncthreads();

    // ---- Q3: fc reduce + ha(t+1) frag commit ----
    {
      const int r = w, lx = l;
      float p = sm.s.lh[r][lx]*sm.s.fcv[lx] + sm.s.lh[r][lx+64]*sm.s.fcv[lx+64];
      p = wsum64(p);
      if (lx == 0) sm.s.yp[r] = p + fcb[0];
    }
    if (dop){
      int r = tid >> 5, d0 = (tid & 31)*4;
      unsigned short* AFH = (unsigned short*)sm.s.afh;
      unsigned short* AFL = (unsigned short*)sm.s.afl;
      int kt = 4 + (d0 >> 5), lane = (((d0 & 31) >> 3) << 4) | r, jj0 = d0 & 7;
      float vv[4] = {pf.x, pf.y, pf.z, pf.w};
#pragma unroll
      for (int p = 0; p < 4; ++p){
        unsigned short h_ = bf16rne(vv[p]);
        AFH[(kt*64 + lane)*8 + jj0 + p] = h_;
        AFL[(kt*64 + lane)*8 + jj0 + p] = bf16rne(vv[p] - bfval(h_));
      }
    }
    __syncthreads();
  }

  if (tid < M) out[b0 + tid] = sm.s.yp[tid];
}

// ================= Fallback (round-3 VALU kernels, if ws too small) ===============
struct FSM1 {
  float x[M][DD]; float h[M][HH]; float c[M][HH];
  float a[M][DD]; float xw[M][DD]; float g[M][NG];
};
struct FP1 { FSM1 s; float red[8][512]; };
union __align__(16) FSMA { FP1 p1; P2 p2; float pad[21504]; };

__global__ __launch_bounds__(NT, 2) void fb_ph12_kernel(
    const float* __restrict__ X,
    const float* __restrict__ saW,  const float* __restrict__ saU,  const float* __restrict__ sab,
    const float* __restrict__ saWa, const float* __restrict__ saUa, const float* __restrict__ saba,
    const float* __restrict__ saVa,
    const float* __restrict__ taWa, const float* __restrict__ taba, const float* __restrict__ taVa,
    float* __restrict__ out, float* __restrict__ Hws)
{
  __shared__ FSMA sm;
  const int tid = threadIdx.x;
  const int b0  = blockIdx.x * M;
  const int w   = tid >> 6, l = tid & 63;

  for (int idx = tid; idx < M*HH; idx += NT){
    int r = idx >> 7, j = idx & 127;
    sm.p1.s.h[r][j] = 0.f; sm.p1.s.c[r][j] = 0.f;
  }
  { int r = tid >> 6, d = tid & 63;
    sm.p1.s.x[r][d] = X[(size_t)(b0+r)*SS*DD + d]; }
  __syncthreads();

  for (int t = 0; t < SS; ++t){
    {
      float pr[M];
#pragma unroll
      for (int r = 0; r < M; ++r) pr[r] = 0.f;
      { const int kb = w*8;
#pragma unroll
        for (int q = 0; q < 2; ++q){
          const int k = kb + q*4;
          const float* wp = saWa + (size_t)k*DD + l;
          float w0 = wp[0], w1 = wp[DD], w2 = wp[2*DD], w3 = wp[3*DD];
#pragma unroll
          for (int r = 0; r < M; ++r){
            float4 v = *(const float4*)&sm.p1.s.x[r][k];
            pr[r] += w0*v.x + w1*v.y + w2*v.z + w3*v.w;
          }
        }
      }
      { const int kb = w*16;
#pragma unroll
        for (int q = 0; q < 4; ++q){
          const int k = kb + q*4;
          const float* wp = saUa + (size_t)k*DD + l;
          float w0 = wp[0], w1 = wp[DD], w2 = wp[2*DD], w3 = wp[3*DD];
#pragma unroll
          for (int r = 0; r < M; ++r){
            float4 v = *(const float4*)&sm.p1.s.h[r][k];
            pr[r] += w0*v.x + w1*v.y + w2*v.z + w3*v.w;
          }
        }
      }
      { const int kb = w*16;
#pragma unroll
        for (int q = 0; q < 4; ++q){
          const int k = kb + q*4;
          const float* wp = saUa + (size_t)(HH + k)*DD + l;
          float w0 = wp[0], w1 = wp[DD], w2 = wp[2*DD], w3 = wp[3*DD];
#pragma unroll
          for (int r = 0; r < M; ++r){
            float4 v = *(const float4*)&sm.p1.s.c[r][k];
            pr[r] += w0*v.x + w1*v.y + w2*v.z + w3*v.w;
          }
        }
      }
#pragma unroll
      for (int r = 0; r < M; ++r) sm.p1.red[w][r*64 + l] = pr[r];
    }
    __syncthreads();
    {
      float s = saba[l];
#pragma unroll
      for (int u = 0; u < 8; ++u) s += sm.p1.red[u][w*64 + l];
      sm.p1.s.a[w][l] = tanhx(s);
    }
    __syncthreads();
    {
      float pr[M];
#pragma unroll
      for (int r = 0; r < M; ++r) pr[r] = 0.f;
      const int kb = w*8;
#pragma unroll
      for (int q = 0; q < 2; ++q){
        const int k = kb + q*4;
        const float* wp = saVa + (size_t)k*DD + l;
        float w0 = wp[0], w1 = wp[DD], w2 = wp[2*DD], w3 = wp[3*DD];
#pragma unroll
        for (int r = 0; r < M; ++r){
          float4 v = *(const float4*)&sm.p1.s.a[r][k];
          pr[r] += w0*v.x + w1*v.y + w2*v.z + w3*v.w;
        }
      }
#pragma unroll
      for (int r = 0; r < M; ++r) sm.p1.red[w][r*64 + l] = pr[r];
    }
    __syncthreads();
    {
      float s = 0.f;
#pragma unroll
      for (int u = 0; u < 8; ++u) s += sm.p1.red[u][w*64 + l];
      float mm = wmax64(s);
      float e  = __expf(s - mm);
      float al = e * (1.0f / wsum64(e));
      out[A_OFF + (size_t)t*BB*DD + (size_t)(b0+w)*DD + l] = al;
      sm.p1.s.xw[w][l] = al * sm.p1.s.x[w][l];
    }
    __syncthreads();
    {
      const int c0 = tid;
      float acc[M];
      const float bv = sab[c0];
#pragma unroll
      for (int r = 0; r < M; ++r) acc[r] = bv;
      for (int k = 0; k < DD; k += 4){
        const float* wp = saW + (size_t)k*NG + c0;
        float w0 = wp[0], w1 = wp[NG], w2 = wp[2*NG], w3 = wp[3*NG];
#pragma unroll
        for (int r = 0; r < M; ++r){
          float4 v = *(const float4*)&sm.p1.s.xw[r][k];
          acc[r] += w0*v.x + w1*v.y + w2*v.z + w3*v.w;
        }
      }
      for (int k = 0; k < HH; k += 4){
        const float* wp = saU + (size_t)k*NG + c0;
        float w0 = wp[0], w1 = wp[NG], w2 = wp[2*NG], w3 = wp[3*NG];
#pragma unroll
        for (int r = 0; r < M; ++r){
          float4 v = *(const float4*)&sm.p1.s.h[r][k];
          acc[r] += w0*v.x + w1*v.y + w2*v.z + w3*v.w;
        }
      }
#pragma unroll
      for (int r = 0; r < M; ++r) sm.p1.s.g[r][c0] = acc[r];
    }
    __syncthreads();
    for (int idx = tid; idx < M*HH; idx += NT){
      int r = idx >> 7, j = idx & 127;
      float iv = sigf (sm.p1.s.g[r][j]);
      float fv = sigf (sm.p1.s.g[r][j +   HH]);
      float gv = tanhx(sm.p1.s.g[r][j + 2*HH]);
      float ov = sigf (sm.p1.s.g[r][j + 3*HH]);
      float cn = fv * sm.p1.s.c[r][j] + iv * gv;
      float hn = ov * tanhx(cn);
      sm.p1.s.c[r][j] = cn; sm.p1.s.h[r][j] = hn;
      Hws[(size_t)(b0+r)*SS*HH + (size_t)t*HH + j] = hn;
    }
    if (t + 1 < SS){
      int r = tid >> 6, d = tid & 63;
      sm.p1.s.x[r][d] = X[(size_t)(b0+r)*SS*DD + (size_t)(t+1)*DD + d];
    }
    __syncthreads();
  }

  for (int r = 0; r < M; ++r){
    float* Hrow = Hws + (size_t)(b0+r)*SS*HH;
    const int c  = tid & 127;
    const int th = tid >> 7;
    float hacc[32];
#pragma unroll
    for (int i = 0; i < 32; ++i) hacc[i] = 0.f;
#pragma unroll
    for (int ch = 0; ch < 4; ++ch){
      for (int idx = tid; idx < 32*HH/4; idx += NT)
        ((float4*)sm.p2.A)[idx] = ((const float4*)(Hrow + (size_t)ch*32*HH))[idx];
      __syncthreads();
      { float acc[8];
        const float bv = taba[c];
#pragma unroll
        for (int i = 0; i < 8; ++i) acc[i] = bv;
        for (int k = 0; k < HH; k += 4){
          const float* wp = taWa + (size_t)k*SS + c;
          float w0 = wp[0], w1 = wp[SS], w2 = wp[2*SS], w3 = wp[3*SS];
#pragma unroll
          for (int i = 0; i < 8; ++i){
            float4 v = *(const float4*)&sm.p2.A[th*8+i][k];
            acc[i] += w0*v.x + w1*v.y + w2*v.z + w3*v.w;
          }
        }
#pragma unroll
        for (int i = 0; i < 8; ++i) sm.p2.tmp[th*8+i][c] = tanhx(acc[i]);
      }
      __syncthreads();
      { float acc[8];
#pragma unroll
        for (int i = 0; i < 8; ++i) acc[i] = 0.f;
        for (int k = 0; k < SS; k += 4){
          const float* wp = taVa + (size_t)k*SS + c;
          float w0 = wp[0], w1 = wp[SS], w2 = wp[2*SS], w3 = wp[3*SS];
#pragma unroll
          for (int i = 0; i < 8; ++i){
            float4 v = *(const float4*)&sm.p2.tmp[th*8+i][k];
            acc[i] += w0*v.x + w1*v.y + w2*v.z + w3*v.w;
          }
        }
#pragma unroll
        for (int i = 0; i < 8; ++i) sm.p2.bp[th*8+i][c] = acc[i];
      }
      __syncthreads();
      { const int wv = tid >> 6, lane = tid & 63;
#pragma unroll
        for (int it = 0; it < 4; ++it){
          int tl = wv + 8*it;
          float v0 = sm.p2.bp[tl][lane], v1 = sm.p2.bp[tl][lane+64];
          float mm = wmax64(fmaxf(v0, v1));
          float e0 = __expf(v0 - mm), e1 = __expf(v1 - mm);
          float inv = 1.0f / wsum64(e0 + e1);
          e0 *= inv; e1 *= inv;
          size_t bo = BETA_OFF + (size_t)(ch*32+tl)*BB*SS + (size_t)(b0+r)*SS;
          out[bo + lane]      = e0;
          out[bo + lane + 64] = e1;
          sm.p2.bp[tl][lane]      = e0;
          sm.p2.bp[tl][lane + 64] = e1;
        }
      }
      __syncthreads();
      for (int k = 0; k < SS; k += 4){
        const float* hp = Hrow + (size_t)k*HH + c;
        float hv0 = hp[0], hv1 = hp[HH], hv2 = hp[2*HH], hv3 = hp[3*HH];
#pragma unroll
        for (int i = 0; i < 8; ++i){
          float4 bv = *(const float4*)&sm.p2.bp[th*8+i][k];
          hacc[ch*8+i] += bv.x*hv0 + bv.y*hv1 + bv.z*hv2 + bv.w*hv3;
        }
      }
    }
    __syncthreads();
#pragma unroll
    for (int ch = 0; ch < 4; ++ch)
#pragma unroll
      for (int i = 0; i < 8; ++i)
        Hrow[(size_t)(ch*32 + th*8 + i)*HH + c] = hacc[ch*8+i];
    __syncthreads();
  }
}

__global__ __launch_bounds__(NT, 2) void fb_ph3_kernel(
    const float* __restrict__ X, const float* __restrict__ Ha,
    const float* __restrict__ taW, const float* __restrict__ taU,
    const float* __restrict__ tab, const float* __restrict__ taWy,
    const float* __restrict__ fcw, const float* __restrict__ fcb,
    float* __restrict__ out)
{
  __shared__ struct {
    float ha[M][HH]; float lh[M][HH]; float lc[M][HH];
    float g[M][NG];  float yp[M];
  } s;
  const int tid = threadIdx.x;
  const int b0  = blockIdx.x * M;

  for (int idx = tid; idx < M*HH; idx += NT){
    int r = idx >> 7, j = idx & 127;
    s.lh[r][j] = 0.f; s.lc[r][j] = 0.f;
  }
  if (tid < M) s.yp[tid] = X[(size_t)(b0+tid)*SS*DD + (DD-1)];
  if (tid < M*HH/4){
    int r = tid >> 5, q = tid & 31;
    ((float4*)s.ha)[tid] = *(const float4*)(Ha + (size_t)(b0+r)*SS*HH + q*4);
  }
  __syncthreads();

  for (int t = 0; t < SS; ++t){
    {
      const int c0 = tid;
      const float wy = taWy[c0];
      const float tb = tab[c0];
      float acc[M];
#pragma unroll
      for (int r = 0; r < M; ++r) acc[r] = tb + s.yp[r]*wy;
      for (int k = 0; k < HH; k += 4){
        const float* wp = taW + (size_t)k*NG + c0;
        float a0 = wp[0], a1 = wp[NG], a2 = wp[2*NG], a3 = wp[3*NG];
#pragma unroll
        for (int r = 0; r < M; ++r){
          float4 v = *(const float4*)&s.ha[r][k];
          acc[r] += a0*v.x + a1*v.y + a2*v.z + a3*v.w;
        }
      }
      for (int k = 0; k < HH; k += 4){
        const float* wp = taU + (size_t)k*NG + c0;
        float a0 = wp[0], a1 = wp[NG], a2 = wp[2*NG], a3 = wp[3*NG];
#pragma unroll
        for (int r = 0; r < M; ++r){
          float4 v = *(const float4*)&s.lh[r][k];
          acc[r] += a0*v.x + a1*v.y + a2*v.z + a3*v.w;
        }
      }
#pragma unroll
      for (int r = 0; r < M; ++r) s.g[r][c0] = acc[r];
    }
    __syncthreads();
    for (int idx = tid; idx < M*HH; idx += NT){
      int r = idx >> 7, j = idx & 127;
      float iv = sigf (s.g[r][j]);
      float fv = sigf (s.g[r][j +   HH]);
      float gv = tanhx(s.g[r][j + 2*HH]);
      float ov = sigf (s.g[r][j + 3*HH]);
      float cn = fv * s.lc[r][j] + iv * gv;
      float hn = ov * tanhx(cn);
      s.lc[r][j] = cn; s.lh[r][j] = hn;
    }
    if (t + 1 < SS && tid < M*HH/4){
      int r = tid >> 5, q = tid & 31;
      ((float4*)s.ha)[tid] =
        *(const float4*)(Ha + (size_t)(b0+r)*SS*HH + (size_t)(t+1)*HH + q*4);
    }
    __syncthreads();
    {
      const int r = tid >> 6, lx = tid & 63;
      float p = s.lh[r][lx]*fcw[lx] + s.lh[r][lx+64]*fcw[lx+64];
      p = wsum64(p);
      if (lx == 0) s.yp[r] = p + fcb[0];
    }
    __syncthreads();
  }
  if (tid < M) out[b0 + tid] = s.yp[tid];
}

extern "C" void kernel_launch(void* const* d_in, const int* in_sizes, int n_in,
                              void* d_out, int out_size, void* d_ws, size_t ws_size,
                              hipStream_t stream) {
  (void)in_sizes; (void)n_in; (void)out_size;
  const float* X    = (const float*)d_in[0];
  const float* saW  = (const float*)d_in[1];
  const float* saU  = (const float*)d_in[2];
  const float* sab  = (const float*)d_in[3];
  const float* saWa = (const float*)d_in[4];
  const float* saUa = (const float*)d_in[5];
  const float* saba = (const float*)d_in[6];
  const float* saVa = (const float*)d_in[7];
  const float* taWa = (const float*)d_in[8];
  // d_in[9] = ta_Ua: unused by the reference forward pass
  const float* taba = (const float*)d_in[10];
  const float* taVa = (const float*)d_in[11];
  const float* taW  = (const float*)d_in[12];
  const float* taU  = (const float*)d_in[13];
  const float* tab  = (const float*)d_in[14];
  const float* taWy = (const float*)d_in[15];
  const float* fcw  = (const float*)d_in[16];
  const float* fcb  = (const float*)d_in[17];
  float* out = (float*)d_out;

  if (ws_size >= NEED_BYTES){
    unsigned short* Fr = (unsigned short*)d_ws;
    float* Hws = (float*)((char*)d_ws + FRAG_BYTES);
    hipLaunchKernelGGL(repack_kernel, dim3(512), dim3(256), 0, stream,
                       saW, saU, saWa, saUa, saVa, taU, taW, taWa, taVa, Fr);
    hipLaunchKernelGGL(mf_ph1_kernel, dim3(BB / M), dim3(NT), 0, stream,
                       X, sab, saba, Fr, out, Hws);
    hipLaunchKernelGGL(ph2_kernel, dim3(BB), dim3(NT), 0, stream,
                       taba, Fr, out, Hws);
    hipLaunchKernelGGL(mf_ph3_kernel, dim3(BB / M), dim3(NT), 0, stream,
                       X, Hws, Fr, tab, taWy, fcw, fcb, out);
  } else {
    float* Hws = (float*)d_ws;
    hipLaunchKernelGGL(fb_ph12_kernel, dim3(BB / M), dim3(NT), 0, stream,
                       X, saW, saU, sab, saWa, saUa, saba, saVa,
                       taWa, taba, taVa, out, Hws);
    hipLaunchKernelGGL(fb_ph3_kernel, dim3(BB / M), dim3(NT), 0, stream,
                       X, Hws, taW, taU, tab, taWy, fcw, fcb, out);
  }
}